// Round 4
// baseline (783.279 us; speedup 1.0000x reference)
//
#include <hip/hip_runtime.h>
#include <hip/hip_cooperative_groups.h>
#include <math.h>

namespace cg = cooperative_groups;

constexpr int HS = 32;      // half spatial (32x32 grids)
constexpr int Lq = 1024;    // HS*HS
constexpr int CN = 128;     // channels
// batches = 2. Inputs fp32 (f, b, mask). Output fp32 (r11-verified).
// R22: SINGLE persistent cooperative kernel, 512 blocks x 256 thr (2 blocks/CU),
// 7 phases separated by grid.sync(). Phase bodies verbatim from r21 (bench-verified,
// absmax 0.015625). Purpose: (a) kill inter-kernel drain/launch bubbles, (b) make the
// aggregate kernel visible in rocprof top-5 (it exceeds the 44us fillBuffer rows) so
// we finally get MfmaUtil/VALUBusy/FETCH/Occupancy for our own code.
// Independent work (Wm gather, mmb) hoisted into phase 0.

typedef short bf16x8 __attribute__((ext_vector_type(8)));
typedef float f32x4  __attribute__((ext_vector_type(4)));

__device__ inline unsigned short f2bf(float x) {   // RNE float->bf16 bits
    union { float f; unsigned int u; } c; c.f = x;
    return (unsigned short)((c.u + 0x7FFF + ((c.u >> 16) & 1)) >> 16);
}
__device__ inline float bf2f(unsigned short h) {
    union { unsigned int u; float f; } c; c.u = ((unsigned int)h) << 16;
    return c.f;
}

// async global->LDS, 16B per lane (wave-uniform LDS base + lane*16 layout)
__device__ inline void gload16(const void* g, void* l) {
    __builtin_amdgcn_global_load_lds(
        (const __attribute__((address_space(1))) unsigned int*)g,
        (__attribute__((address_space(3))) unsigned int*)l, 16, 0, 0);
}

__global__ __launch_bounds__(256, 2) void k_mega(const float* __restrict__ f,
                                                 const float* __restrict__ bsrc,
                                                 const float* __restrict__ mask,
                                                 float* __restrict__ out,
                                                 float* __restrict__ ws) {
    // ---- workspace layout (identical to r21 host-side layout) ----
    float* ssq   = ws;                        // 2048
    float* norms = ssq   + 2048;              // 2048
    float* mmb   = norms + 2048;              // 1024
    unsigned short* fH = (unsigned short*)(mmb + 1024);      // 262144 ushorts each
    unsigned short* fL = fH + 262144;
    unsigned short* bH = fL + 262144;
    unsigned short* bL = bH + 262144;
    float* GTa   = (float*)(bL + 262144);     // 2097152 : GT -> attnT(bf16)
    float* C1    = GTa + 2097152;             // 2097152 : S0T -> P[0:2M]
    float* C2    = C1  + 2097152;             // 2097152 : S2T -> P[2M:4M]
    unsigned short* Wm = (unsigned short*)(C2 + 2097152);    // 4194304 ushorts
    float* S0T  = C1;
    float* S2T  = C2;
    unsigned short* attnT = (unsigned short*)GTa;  // GT dead after s0T phase
    float* P    = C1;      // spans C1+C2; S0T dead after fuse12, S2T dead after softmax

    __shared__ __align__(16) unsigned short As[128 * 64];   // 16 KB (gemm phase)
    __shared__ __align__(16) unsigned short Bs[64 * 64];    //  8 KB (gemm phase)

    cg::grid_group grid = cg::this_grid();
    const int NB = gridDim.x;                 // 512
    const int tx = threadIdx.x;

    // ================= P0: prep seg1 (512) + Wm gather (4096) + mmb (4) =================
    for (int vb = blockIdx.x; vb < 4612; vb += NB) {
        if (vb < 512) {
            int u = vb * 4 + (tx >> 6);       // 0..2047 = bb*1024 + p
            int lane = tx & 63;
            int p = u & (Lq - 1), bb = u >> 10;
            int py = p >> 5, px = p & 31;
            long srcbase = (((long)bb * CN) * 64 + 2 * py) * 64 + 2 * px;
            float s = 0.f;
#pragma unroll
            for (int i = 0; i < 2; ++i) {
                int c = lane + i * 64;
                long src = srcbase + (long)c * 4096;
                float fv = f[src], bv = bsrc[src];
                int o = u * CN + c;
                unsigned short fh = f2bf(fv), bh = f2bf(bv);
                fH[o] = fh; fL[o] = f2bf(fv - bf2f(fh));
                bH[o] = bh; bL[o] = f2bf(bv - bf2f(bh));
                s += bv * bv;
            }
            for (int off = 32; off > 0; off >>= 1) s += __shfl_down(s, off, 64);
            if (lane == 0) ssq[u] = s;
        } else if (vb < 4608) {
            int idx4 = (vb - 512) * 256 + tx; // 0..1048575 (4 outputs each)
            int qg = (idx4 & 255) << 2;
            int m  = (idx4 >> 8) & 2047;
            int bb = idx4 >> 19;
            int c = m >> 4, u = (m >> 2) & 3, v = m & 3;
            int qy = qg >> 5, qx0 = qg & 31;
            int y = 2 * qy + u - 1;
            bool yok = (unsigned)y < 64u;
            const float* brow = bsrc + (((long)bb * CN + c) * 64 + (yok ? y : 0)) * 64;
            ushort4 w;
            unsigned short* wp = (unsigned short*)&w;
#pragma unroll
            for (int j = 0; j < 4; ++j) {
                int x = 2 * (qx0 + j) + v - 1;
                float val = (yok && (unsigned)x < 64u) ? brow[x] : 0.f;
                wp[j] = f2bf(val);
            }
            *(ushort4*)&Wm[(long)idx4 << 2] = w;
        } else {
            int q = (vb - 4608) * 256 + tx;   // 0..1023
            int qy = q >> 5, qx = q & 31;
            float s = 0.f;
            for (int dk = -1; dk <= 1; ++dk) {
                int y = qy + dk; if ((unsigned)y >= (unsigned)HS) continue;
                for (int dl = -1; dl <= 1; ++dl) {
                    int x = qx + dl; if ((unsigned)x >= (unsigned)HS) continue;
                    s += mask[(8 * y) * 256 + 8 * x];
                }
            }
            mmb[q] = (s == 0.0f) ? 1.0f : 0.0f;
        }
    }
    __threadfence(); grid.sync();

    // ================= P1: gram MFMA (512) + norms (8) =================
    for (int vb = blockIdx.x; vb < 520; vb += NB) {
        if (vb < 512) {
            int bx = vb & 15, by = (vb >> 4) & 15;
            long bz = vb >> 8;
            const unsigned short* AH = fH + bz * 131072;
            const unsigned short* AL = fL + bz * 131072;
            const unsigned short* BH = bH + bz * 131072;
            const unsigned short* BL = bL + bz * 131072;
            float* C = GTa + (bz << 20);
            int w = tx >> 6, lane = tx & 63, quad = lane >> 4, l16 = lane & 15;
            int wm = bx * 64 + (w & 1) * 32;
            int wn = by * 64 + (w >> 1) * 32;
            int ko = quad * 8;
            f32x4 acc[2][2] = {};
#pragma unroll
            for (int k0 = 0; k0 < 128; k0 += 32) {
                bf16x8 ah0 = *(const bf16x8*)&AH[(wm + l16) * 128 + ko + k0];
                bf16x8 ah1 = *(const bf16x8*)&AH[(wm + 16 + l16) * 128 + ko + k0];
                bf16x8 al0 = *(const bf16x8*)&AL[(wm + l16) * 128 + ko + k0];
                bf16x8 al1 = *(const bf16x8*)&AL[(wm + 16 + l16) * 128 + ko + k0];
                bf16x8 bh0 = *(const bf16x8*)&BH[(wn + l16) * 128 + ko + k0];
                bf16x8 bh1 = *(const bf16x8*)&BH[(wn + 16 + l16) * 128 + ko + k0];
                bf16x8 bl0 = *(const bf16x8*)&BL[(wn + l16) * 128 + ko + k0];
                bf16x8 bl1 = *(const bf16x8*)&BL[(wn + 16 + l16) * 128 + ko + k0];
                acc[0][0] = __builtin_amdgcn_mfma_f32_16x16x32_bf16(ah0, bh0, acc[0][0], 0, 0, 0);
                acc[0][1] = __builtin_amdgcn_mfma_f32_16x16x32_bf16(ah0, bh1, acc[0][1], 0, 0, 0);
                acc[1][0] = __builtin_amdgcn_mfma_f32_16x16x32_bf16(ah1, bh0, acc[1][0], 0, 0, 0);
                acc[1][1] = __builtin_amdgcn_mfma_f32_16x16x32_bf16(ah1, bh1, acc[1][1], 0, 0, 0);
                acc[0][0] = __builtin_amdgcn_mfma_f32_16x16x32_bf16(ah0, bl0, acc[0][0], 0, 0, 0);
                acc[0][1] = __builtin_amdgcn_mfma_f32_16x16x32_bf16(ah0, bl1, acc[0][1], 0, 0, 0);
                acc[1][0] = __builtin_amdgcn_mfma_f32_16x16x32_bf16(ah1, bl0, acc[1][0], 0, 0, 0);
                acc[1][1] = __builtin_amdgcn_mfma_f32_16x16x32_bf16(ah1, bl1, acc[1][1], 0, 0, 0);
                acc[0][0] = __builtin_amdgcn_mfma_f32_16x16x32_bf16(al0, bh0, acc[0][0], 0, 0, 0);
                acc[0][1] = __builtin_amdgcn_mfma_f32_16x16x32_bf16(al0, bh1, acc[0][1], 0, 0, 0);
                acc[1][0] = __builtin_amdgcn_mfma_f32_16x16x32_bf16(al1, bh0, acc[1][0], 0, 0, 0);
                acc[1][1] = __builtin_amdgcn_mfma_f32_16x16x32_bf16(al1, bh1, acc[1][1], 0, 0, 0);
            }
#pragma unroll
            for (int i = 0; i < 2; ++i)
#pragma unroll
                for (int j = 0; j < 2; ++j) {
                    int mrow = wm + i * 16 + quad * 4;
                    int ncol = wn + j * 16 + l16;
#pragma unroll
                    for (int r = 0; r < 4; ++r)
                        C[(long)(mrow + r) * Lq + ncol] = acc[i][j][r];
                }
        } else {
            int idx = (vb - 512) * 256 + tx;  // 0..2047
            int q = idx & (Lq - 1);
            int bb = idx >> 10;
            int qy = q >> 5, qx = q & 31;
            float s = 0.1152f;
            for (int dk = -1; dk <= 1; ++dk) {
                int y = qy + dk; if ((unsigned)y >= (unsigned)HS) continue;
                for (int dl = -1; dl <= 1; ++dl) {
                    int x = qx + dl; if ((unsigned)x >= (unsigned)HS) continue;
                    s += ssq[bb * Lq + y * HS + x];
                }
            }
            norms[idx] = sqrtf(s);
        }
    }
    __threadfence(); grid.sync();

    // ================= P2: s0T (2048 vblocks, 4 q-outputs/thread) =================
    for (int vb = blockIdx.x; vb < 2048; vb += NB) {
        int idx4 = vb * 256 + tx;
        int qg = (idx4 & 255) << 2;
        int pp = (idx4 >> 8) & (Lq - 1);
        int bb = idx4 >> 18;
        int qy = qg >> 5, qx0 = qg & 31, py = pp >> 5, px = pp & 31;
        const float* Gb = GTa + ((long)bb << 20);
        float acc[4] = {0.f, 0.f, 0.f, 0.f};
#pragma unroll
        for (int dk = -1; dk <= 1; ++dk) {
            if ((unsigned)(qy + dk) >= (unsigned)HS || (unsigned)(py + dk) >= (unsigned)HS) continue;
#pragma unroll
            for (int dl = -1; dl <= 1; ++dl) {
                if ((unsigned)(px + dl) >= (unsigned)HS) continue;
                int sft = dk * HS + dl;
                const float* rp = Gb + (long)(pp + sft) * Lq + (qg + sft);
#pragma unroll
                for (int j = 0; j < 4; ++j)
                    if ((unsigned)(qx0 + j + dl) < (unsigned)HS) acc[j] += rp[j];
            }
        }
        const float* nb = norms + bb * Lq + qg;
        float4 o = { acc[0] / nb[0], acc[1] / nb[1], acc[2] / nb[2], acc[3] / nb[3] };
        *(float4*)&S0T[((long)bb << 20) + ((long)pp << 10) + qg] = o;
    }
    __threadfence(); grid.sync();

    // ================= P3: fuse12 (2048 vblocks, 4 p-outputs/thread) =================
    for (int vb = blockIdx.x; vb < 2048; vb += NB) {
        int idx4 = vb * 256 + tx;
        int pg = (idx4 & 255) << 2;
        int q  = (idx4 >> 8) & (Lq - 1);
        int bb = idx4 >> 18;
        int hb = q >> 5, wb = q & 31, hf = pg >> 5, wf0 = pg & 31;
        int ip = wb * HS + hb, jp0 = wf0 * HS + hf;
        const float* S = S0T + (long)bb * Lq * Lq;
        float acc[4] = {0.f, 0.f, 0.f, 0.f};
#pragma unroll
        for (int d = -1; d <= 1; ++d) {
            int t = ip + d;
            if ((unsigned)t >= (unsigned)Lq) continue;
            int q2 = (t & 31) * HS + (t >> 5);
            int r0 = jp0 + d;
            int p20 = (r0 & 31) * HS + (r0 >> 5);
            long rowb = (long)q2 * Lq;
#pragma unroll
            for (int j = 0; j < 4; ++j) {
                int r = r0 + 32 * j;
                if ((unsigned)r >= (unsigned)Lq) continue;
                int p2 = p20 + j;
                long base = rowb + p2;
                float v = S[base];
                if (q2 > 0 && p2 > 0)             v += S[base - (Lq + 1)];
                if (q2 < Lq - 1 && p2 < Lq - 1)   v += S[base + (Lq + 1)];
                acc[j] += v;
            }
        }
        float4 o = { acc[0], acc[1], acc[2], acc[3] };
        *(float4*)&S2T[((long)bb << 20) + ((long)q << 10) + pg] = o;
    }
    __threadfence(); grid.sync();

    // ================= P4: row softmax -> attnT bf16 (512 vblocks) =================
    for (int vb = blockIdx.x; vb < 512; vb += NB) {
        int wid = vb * 4 + (tx >> 6);      // 0..2047
        int lane = tx & 63;
        int bb = wid >> 10, p = wid & (Lq - 1);
        const float* row = S2T + ((long)bb << 20) + (long)p * Lq;
        unsigned short* orow = attnT + ((long)bb << 20) + (long)p * Lq;
        float x[16]; float mx = -1e30f;
#pragma unroll
        for (int i = 0; i < 16; ++i) {
            int q = i * 64 + lane;
            x[i] = row[q] * mmb[q] * 10.0f;
            mx = fmaxf(mx, x[i]);
        }
        for (int off = 32; off > 0; off >>= 1) mx = fmaxf(mx, __shfl_xor(mx, off, 64));
        float e[16]; float s = 0.f;
#pragma unroll
        for (int i = 0; i < 16; ++i) { e[i] = __expf(x[i] - mx); s += e[i]; }
        for (int off = 32; off > 0; off >>= 1) s += __shfl_xor(s, off, 64);
        float inv = 1.0f / s;
#pragma unroll
        for (int i = 0; i < 16; ++i) {
            int q = i * 64 + lane;
            orow[q] = f2bf(e[i] * mmb[q] * inv);
        }
    }
    __threadfence(); grid.sync();

    // ================= P5: MFMA GEMM m97-style (512 vblocks = exactly 1/block) =================
    for (int vb = blockIdx.x; vb < 512; vb += NB) {
        int bx = vb & 15, by = (vb >> 4) & 15;
        long bz = vb >> 8;
        const unsigned short* A = Wm + bz * (2048L * Lq);
        const unsigned short* B = attnT + bz * ((long)Lq * Lq);
        float* C = P + bz * (2048L * Lq);
        int w = tx >> 6, lane = tx & 63, quad = lane >> 4, l16 = lane & 15;
        int wr = w >> 1, wc = w & 1;
        int m0 = bx * 128, n0 = by * 64;
        int srow = tx >> 3;
        int scol = (tx & 7) * 8;
        f32x4 acc[4][2] = {};
        for (int k0 = 0; k0 < Lq; k0 += 64) {
            __syncthreads();
#pragma unroll
            for (int r = 0; r < 4; ++r)
                gload16(A + (long)(m0 + r * 32 + srow) * Lq + k0 + scol,
                        &As[(r * 32 + srow) * 64 + scol]);
#pragma unroll
            for (int r = 0; r < 2; ++r)
                gload16(B + (long)(n0 + r * 32 + srow) * Lq + k0 + scol,
                        &Bs[(r * 32 + srow) * 64 + scol]);
            __syncthreads();
#pragma unroll
            for (int ks = 0; ks < 2; ++ks) {
                bf16x8 a[4], b[2];
#pragma unroll
                for (int i = 0; i < 4; ++i)
                    a[i] = *(const bf16x8*)&As[(wr * 64 + i * 16 + l16) * 64 + ks * 32 + quad * 8];
#pragma unroll
                for (int j = 0; j < 2; ++j)
                    b[j] = *(const bf16x8*)&Bs[(wc * 32 + j * 16 + l16) * 64 + ks * 32 + quad * 8];
#pragma unroll
                for (int i = 0; i < 4; ++i)
#pragma unroll
                    for (int j = 0; j < 2; ++j)
                        acc[i][j] = __builtin_amdgcn_mfma_f32_16x16x32_bf16(a[i], b[j], acc[i][j], 0, 0, 0);
            }
        }
#pragma unroll
        for (int i = 0; i < 4; ++i) {
            int mrow = m0 + wr * 64 + i * 16 + quad * 4;
#pragma unroll
            for (int j = 0; j < 2; ++j) {
                int ncol = n0 + wc * 32 + j * 16 + l16;
#pragma unroll
                for (int r = 0; r < 4; ++r)
                    C[(long)(mrow + r) * Lq + ncol] = acc[i][j][r];
            }
        }
    }
    __threadfence(); grid.sync();

    // ================= P6: conv epilogue (1024 vblocks, 4 ox-outputs/thread) =================
    for (int vb = blockIdx.x; vb < 1024; vb += NB) {
        int idx4 = vb * 256 + tx;
        int ox0 = (idx4 & 15) << 2;
        int oy  = (idx4 >> 4) & 63;
        int c   = (idx4 >> 10) & 127;
        int bb  = idx4 >> 17;
        const float* Pb = P + (long)bb * 2048 * Lq;
        float acc[4] = {0.f, 0.f, 0.f, 0.f};
#pragma unroll
        for (int u = 0; u < 4; ++u) {
            int t = oy + u - 2;
            if (t & 1) continue;
            int iy = t >> 1;
            if ((unsigned)iy >= (unsigned)HS) continue;
#pragma unroll
            for (int v = 0; v < 4; ++v) {
                const float* prow = &Pb[(long)((c << 4) + (3 - u) * 4 + (3 - v)) * Lq + (iy << 5)];
#pragma unroll
                for (int j = 0; j < 4; ++j) {
                    int r = ox0 + j + v - 2;
                    if (r & 1) continue;
                    int ix = r >> 1;
                    if ((unsigned)ix >= (unsigned)HS) continue;
                    acc[j] += prow[ix];
                }
            }
        }
        float4 o = { 0.25f * acc[0], 0.25f * acc[1], 0.25f * acc[2], 0.25f * acc[3] };
        *(float4*)&out[(long)idx4 << 2] = o;
    }
}

extern "C" void kernel_launch(void* const* d_in, const int* in_sizes, int n_in,
                              void* d_out, int out_size, void* d_ws, size_t ws_size,
                              hipStream_t stream) {
    const float* f    = (const float*)d_in[0];
    const float* bsrc = (const float*)d_in[1];
    const float* mask = (const float*)d_in[2];
    float* out = (float*)d_out;
    float* ws = (float*)d_ws;

    void* kargs[] = { (void*)&f, (void*)&bsrc, (void*)&mask, (void*)&out, (void*)&ws };
    hipLaunchCooperativeKernel((const void*)k_mega, dim3(512), dim3(256), kargs, 0, stream);
}

// Round 5
// 155.036 us; speedup vs baseline: 5.0522x; 5.0522x over previous
//
#include <hip/hip_runtime.h>
#include <hip/hip_bf16.h>
#include <math.h>

constexpr int HS = 32;      // half spatial (32x32 grids)
constexpr int Lq = 1024;    // HS*HS
constexpr int CN = 128;     // channels
// batches = 2. Inputs fp32 (f, b, mask). Output fp32 (r11-verified).
// R23: base = r19 (143.99 best). Changes:
//  (a) k_nm merged into k_gram as blockIdx.z==2 segment (r21-verified code) — -1 launch.
//  (b) epi2 fused into gemm epilogue via predicated atomicAdd scatter (each acc elem
//      maps to <=1 output: oy=2iy+quad-1, ox=2ix+r-1, c=bx*8+wr*4+i). out zero-init
//      as a third prep3 grid segment (2 levels earlier, stream-ordered). -1 launch,
//      -16MB P write, -16MB P read. Final-sum order changes by <=2ulp (absmax drift ~1e-6).
// R22 lesson: dur_us includes ~56us harness floor (workspace poison fill + restores);
// our controllable span is ~88us. Coop/grid.sync refuted (occupancy collapse).

typedef short bf16x8 __attribute__((ext_vector_type(8)));
typedef float f32x4  __attribute__((ext_vector_type(4)));

__device__ inline unsigned short f2bf(float x) {   // RNE float->bf16 bits
    union { float f; unsigned int u; } c; c.f = x;
    return (unsigned short)((c.u + 0x7FFF + ((c.u >> 16) & 1)) >> 16);
}
__device__ inline float bf2f(unsigned short h) {
    union { unsigned int u; float f; } c; c.u = ((unsigned int)h) << 16;
    return c.f;
}

// async global->LDS, 16B per lane (wave-uniform LDS base + lane*16 layout)
__device__ inline void gload16(const void* g, void* l) {
    __builtin_amdgcn_global_load_lds(
        (const __attribute__((address_space(1))) unsigned int*)g,
        (__attribute__((address_space(3))) unsigned int*)l, 16, 0, 0);
}

// ---------------- merged prep+ssq+wm+outzero: one launch, three grid segments ----------------
__global__ __launch_bounds__(256) void k_prep3(const float* __restrict__ f,
                                               const float* __restrict__ bsrc,
                                               unsigned short* __restrict__ fH, unsigned short* __restrict__ fL,
                                               unsigned short* __restrict__ bH, unsigned short* __restrict__ bL,
                                               float* __restrict__ ssq,
                                               unsigned short* __restrict__ Wm,
                                               float* __restrict__ out) {
    int tx = threadIdx.x;
    if (blockIdx.x < 512) {
        int u = blockIdx.x * 4 + (tx >> 6);  // 0..2047 = bb*1024 + p
        int lane = tx & 63;
        int p = u & (Lq - 1), bb = u >> 10;
        int py = p >> 5, px = p & 31;
        long srcbase = (((long)bb * CN) * 64 + 2 * py) * 64 + 2 * px;
        float s = 0.f;
#pragma unroll
        for (int i = 0; i < 2; ++i) {
            int c = lane + i * 64;
            long src = srcbase + (long)c * 4096;
            float fv = f[src], bv = bsrc[src];
            int o = u * CN + c;
            unsigned short fh = f2bf(fv), bh = f2bf(bv);
            fH[o] = fh; fL[o] = f2bf(fv - bf2f(fh));
            bH[o] = bh; bL[o] = f2bf(bv - bf2f(bh));
            s += bv * bv;
        }
        for (int off = 32; off > 0; off >>= 1) s += __shfl_down(s, off, 64);
        if (lane == 0) ssq[u] = s;
    } else if (blockIdx.x < 16896) {
        int idx = (blockIdx.x - 512) * 256 + tx;   // 2*2048*1024
        int q  = idx & (Lq - 1);
        int m  = (idx >> 10) & 2047;
        int bb = idx >> 21;
        int c = m >> 4, u = (m >> 2) & 3, v = m & 3;
        int qy = q >> 5, qx = q & 31;
        int y = 2 * qy + u - 1, x = 2 * qx + v - 1;
        float val = 0.f;
        if ((unsigned)y < 64u && (unsigned)x < 64u)
            val = bsrc[(((long)bb * CN + c) * 64 + y) * 64 + x];
        Wm[idx] = f2bf(val);
    } else {
        // zero-init out (1,048,576 floats = 262,144 float4) for gemm's atomic scatter
        int idx = (blockIdx.x - 16896) * 256 + tx;  // 0..262143
        float4 z = {0.f, 0.f, 0.f, 0.f};
        *(float4*)&out[(long)idx << 2] = z;
    }
}

// ---------------- Gram MFMA bf16x2 + merged nm segment (blockIdx.z==2) ----------------
__global__ __launch_bounds__(256) void k_gram(const unsigned short* __restrict__ fH,
                                              const unsigned short* __restrict__ fL,
                                              const unsigned short* __restrict__ bH,
                                              const unsigned short* __restrict__ bL,
                                              float* __restrict__ GT,
                                              const float* __restrict__ ssq, const float* __restrict__ mask,
                                              float* __restrict__ norms, float* __restrict__ mmb) {
    if (blockIdx.z == 2) {                    // ---- nm segment (12 active blocks) ----
        int blk = blockIdx.y * 16 + blockIdx.x;
        if (blk >= 12) return;
        int idx = blk * 256 + threadIdx.x;    // 0..3071
        if (idx < 2048) {
            int q = idx & (Lq - 1);
            int bb = idx >> 10;
            int qy = q >> 5, qx = q & 31;
            float s = 0.1152f;
            for (int dk = -1; dk <= 1; ++dk) {
                int y = qy + dk; if ((unsigned)y >= (unsigned)HS) continue;
                for (int dl = -1; dl <= 1; ++dl) {
                    int x = qx + dl; if ((unsigned)x >= (unsigned)HS) continue;
                    s += ssq[bb * Lq + y * HS + x];
                }
            }
            norms[idx] = sqrtf(s);
        } else if (idx < 3072) {
            int q = idx - 2048;               // 0..1023
            int qy = q >> 5, qx = q & 31;
            float s = 0.f;
            for (int dk = -1; dk <= 1; ++dk) {
                int y = qy + dk; if ((unsigned)y >= (unsigned)HS) continue;
                for (int dl = -1; dl <= 1; ++dl) {
                    int x = qx + dl; if ((unsigned)x >= (unsigned)HS) continue;
                    s += mask[(8 * y) * 256 + 8 * x];
                }
            }
            mmb[q] = (s == 0.0f) ? 1.0f : 0.0f;
        }
        return;
    }
    const long bz = blockIdx.z;
    const unsigned short* AH = fH + bz * 131072;
    const unsigned short* AL = fL + bz * 131072;
    const unsigned short* BH = bH + bz * 131072;
    const unsigned short* BL = bL + bz * 131072;
    float* C = GT + (bz << 20);
    int t = threadIdx.x, w = t >> 6, lane = t & 63, quad = lane >> 4, l16 = lane & 15;
    int wm = blockIdx.x * 64 + (w & 1) * 32;
    int wn = blockIdx.y * 64 + (w >> 1) * 32;
    int ko = quad * 8;
    f32x4 acc[2][2] = {};
#pragma unroll
    for (int k0 = 0; k0 < 128; k0 += 32) {
        bf16x8 ah0 = *(const bf16x8*)&AH[(wm + l16) * 128 + ko + k0];
        bf16x8 ah1 = *(const bf16x8*)&AH[(wm + 16 + l16) * 128 + ko + k0];
        bf16x8 al0 = *(const bf16x8*)&AL[(wm + l16) * 128 + ko + k0];
        bf16x8 al1 = *(const bf16x8*)&AL[(wm + 16 + l16) * 128 + ko + k0];
        bf16x8 bh0 = *(const bf16x8*)&BH[(wn + l16) * 128 + ko + k0];
        bf16x8 bh1 = *(const bf16x8*)&BH[(wn + 16 + l16) * 128 + ko + k0];
        bf16x8 bl0 = *(const bf16x8*)&BL[(wn + l16) * 128 + ko + k0];
        bf16x8 bl1 = *(const bf16x8*)&BL[(wn + 16 + l16) * 128 + ko + k0];
        acc[0][0] = __builtin_amdgcn_mfma_f32_16x16x32_bf16(ah0, bh0, acc[0][0], 0, 0, 0);
        acc[0][1] = __builtin_amdgcn_mfma_f32_16x16x32_bf16(ah0, bh1, acc[0][1], 0, 0, 0);
        acc[1][0] = __builtin_amdgcn_mfma_f32_16x16x32_bf16(ah1, bh0, acc[1][0], 0, 0, 0);
        acc[1][1] = __builtin_amdgcn_mfma_f32_16x16x32_bf16(ah1, bh1, acc[1][1], 0, 0, 0);
        acc[0][0] = __builtin_amdgcn_mfma_f32_16x16x32_bf16(ah0, bl0, acc[0][0], 0, 0, 0);
        acc[0][1] = __builtin_amdgcn_mfma_f32_16x16x32_bf16(ah0, bl1, acc[0][1], 0, 0, 0);
        acc[1][0] = __builtin_amdgcn_mfma_f32_16x16x32_bf16(ah1, bl0, acc[1][0], 0, 0, 0);
        acc[1][1] = __builtin_amdgcn_mfma_f32_16x16x32_bf16(ah1, bl1, acc[1][1], 0, 0, 0);
        acc[0][0] = __builtin_amdgcn_mfma_f32_16x16x32_bf16(al0, bh0, acc[0][0], 0, 0, 0);
        acc[0][1] = __builtin_amdgcn_mfma_f32_16x16x32_bf16(al0, bh1, acc[0][1], 0, 0, 0);
        acc[1][0] = __builtin_amdgcn_mfma_f32_16x16x32_bf16(al1, bh0, acc[1][0], 0, 0, 0);
        acc[1][1] = __builtin_amdgcn_mfma_f32_16x16x32_bf16(al1, bh1, acc[1][1], 0, 0, 0);
    }
#pragma unroll
    for (int i = 0; i < 2; ++i)
#pragma unroll
        for (int j = 0; j < 2; ++j) {
            int mrow = wm + i * 16 + quad * 4;
            int ncol = wn + j * 16 + l16;
#pragma unroll
            for (int r = 0; r < 4; ++r)
                C[(long)(mrow + r) * Lq + ncol] = acc[i][j][r];
        }
}

// ---------------- S0T[p][q] = band9(GT) / norms[q]  (T-layout, r14-verified) ----------------
__global__ __launch_bounds__(256) void k_s0T(const float* __restrict__ GT, const float* __restrict__ norms,
                                             float* __restrict__ S0T) {
    int idx = blockIdx.x * 256 + threadIdx.x;  // 2*1024*1024
    int q  = idx & (Lq - 1);
    int pp = (idx >> 10) & (Lq - 1);
    int bb = idx >> 20;
    int qy = q >> 5, qx = q & 31, py = pp >> 5, px = pp & 31;
    const float* Gb = GT + ((long)bb << 20);
    float s = 0.f;
#pragma unroll
    for (int dk = -1; dk <= 1; ++dk) {
        if ((unsigned)(qy + dk) >= (unsigned)HS || (unsigned)(py + dk) >= (unsigned)HS) continue;
#pragma unroll
        for (int dl = -1; dl <= 1; ++dl) {
            if ((unsigned)(qx + dl) >= (unsigned)HS || (unsigned)(px + dl) >= (unsigned)HS) continue;
            int sft = dk * HS + dl;
            s += Gb[(long)(pp + sft) * Lq + (q + sft)];
        }
    }
    S0T[idx] = s / norms[bb * Lq + q];
}

// ---------------- FUSED fuse1+fuse2 on T layout (r14/r16-verified) ----------------
__global__ __launch_bounds__(256) void k_fuse12(const float* __restrict__ S0, float* __restrict__ S2) {
    int idx = blockIdx.x * 256 + threadIdx.x;   // 2*1024*1024
    int p  = idx & (Lq - 1);
    int q  = (idx >> 10) & (Lq - 1);
    int bb = idx >> 20;
    int hb = q >> 5, wb = q & 31, hf = p >> 5, wf = p & 31;
    int ip = wb * HS + hb, jp = wf * HS + hf;
    const float* S = S0 + (long)bb * Lq * Lq;
    float s = 0.f;
#pragma unroll
    for (int d = -1; d <= 1; ++d) {
        int t = ip + d, r = jp + d;
        if ((unsigned)t < (unsigned)Lq && (unsigned)r < (unsigned)Lq) {
            int q2 = (t & 31) * HS + (t >> 5);
            int p2 = (r & 31) * HS + (r >> 5);
            long base = (long)q2 * Lq + p2;
            float v = S[base];
            if (q2 > 0 && p2 > 0)             v += S[base - (Lq + 1)];
            if (q2 < Lq - 1 && p2 < Lq - 1)   v += S[base + (Lq + 1)];
            s += v;
        }
    }
    S2[idx] = s;
}

// ---------------- row softmax over q on S2T[p][q]; writes attnT bf16 [p][q] (r13-verified) ----------------
__global__ __launch_bounds__(256) void k_softmaxT(const float* __restrict__ S2T, const float* __restrict__ mmb,
                                                  unsigned short* __restrict__ At) {
    int wid = blockIdx.x * 4 + (threadIdx.x >> 6);   // 0..2047
    int lane = threadIdx.x & 63;
    int bb = wid >> 10, p = wid & (Lq - 1);
    const float* row = S2T + ((long)bb << 20) + (long)p * Lq;
    unsigned short* orow = At + ((long)bb << 20) + (long)p * Lq;
    float x[16]; float mx = -1e30f;
#pragma unroll
    for (int i = 0; i < 16; ++i) {
        int q = i * 64 + lane;
        x[i] = row[q] * mmb[q] * 10.0f;
        mx = fmaxf(mx, x[i]);
    }
    for (int off = 32; off > 0; off >>= 1) mx = fmaxf(mx, __shfl_xor(mx, off, 64));
    float e[16]; float s = 0.f;
#pragma unroll
    for (int i = 0; i < 16; ++i) { e[i] = __expf(x[i] - mx); s += e[i]; }
    for (int off = 32; off > 0; off >>= 1) s += __shfl_xor(s, off, 64);
    float inv = 1.0f / s;
#pragma unroll
    for (int i = 0; i < 16; ++i) {
        int q = i * 64 + lane;
        orow[q] = f2bf(e[i] * mmb[q] * inv);
    }
}

// ---------------- MFMA GEMM m97-style + FUSED conv epilogue (atomic scatter) ----------------
// P[m][p] = sum_q Wm[m][q]*attnT[p][q]; each P elem feeds <=1 output:
// c = mrow>>4, u = 3-quad, v = 3-r, oy = 2*iy+quad-1, ox = 2*ix+r-1.
// out zero-initialized by prep3 segment 3 (stream-ordered, 2 levels earlier).
__global__ __launch_bounds__(256) void k_gemm_mfma(const unsigned short* __restrict__ WmA,
                                                   const unsigned short* __restrict__ At,
                                                   float* __restrict__ out) {
    const long bz = blockIdx.z;
    const unsigned short* A = WmA + bz * (2048L * Lq);
    const unsigned short* B = At  + bz * ((long)Lq * Lq);
    __shared__ __align__(16) unsigned short As[128 * 64];   // 16 KB
    __shared__ __align__(16) unsigned short Bs[64 * 64];    //  8 KB
    int t = threadIdx.x;
    int w = t >> 6, lane = t & 63, quad = lane >> 4, l16 = lane & 15;
    int wr = w >> 1, wc = w & 1;             // wave tile: rows wr*64.., cols wc*32..
    int m0 = blockIdx.x * 128, n0 = blockIdx.y * 64;
    int srow = t >> 3;                        // 0..31: row within a 32-row staging round
    int scol = (t & 7) * 8;                   // element col of this thread's 16B
    f32x4 acc[4][2] = {};
    for (int k0 = 0; k0 < Lq; k0 += 64) {
        __syncthreads();                      // previous iter's LDS reads complete
#pragma unroll
        for (int r = 0; r < 4; ++r)           // A: 128 rows = 4 rounds
            gload16(A + (long)(m0 + r * 32 + srow) * Lq + k0 + scol,
                    &As[(r * 32 + srow) * 64 + scol]);
#pragma unroll
        for (int r = 0; r < 2; ++r)           // B: 64 rows = 2 rounds
            gload16(B + (long)(n0 + r * 32 + srow) * Lq + k0 + scol,
                    &Bs[(r * 32 + srow) * 64 + scol]);
        __syncthreads();                      // compiler drains vmcnt here
#pragma unroll
        for (int ks = 0; ks < 2; ++ks) {
            bf16x8 a[4], b[2];
#pragma unroll
            for (int i = 0; i < 4; ++i)
                a[i] = *(const bf16x8*)&As[(wr * 64 + i * 16 + l16) * 64 + ks * 32 + quad * 8];
#pragma unroll
            for (int j = 0; j < 2; ++j)
                b[j] = *(const bf16x8*)&Bs[(wc * 32 + j * 16 + l16) * 64 + ks * 32 + quad * 8];
#pragma unroll
            for (int i = 0; i < 4; ++i)
#pragma unroll
                for (int j = 0; j < 2; ++j)
                    acc[i][j] = __builtin_amdgcn_mfma_f32_16x16x32_bf16(a[i], b[j], acc[i][j], 0, 0, 0);
        }
    }
    // fused epilogue: scatter 0.25*acc into out with predication (replaces P store + k_epi2)
    float* ob = out + ((long)bz << 19);       // bz*128*64*64
#pragma unroll
    for (int i = 0; i < 4; ++i) {
        int c = (m0 + wr * 64 + i * 16) >> 4; // const over quad*4+r (<16)
#pragma unroll
        for (int j = 0; j < 2; ++j) {
            int ncol = n0 + wc * 32 + j * 16 + l16;
            int iy = ncol >> 5, ix = ncol & 31;
            int oy = 2 * iy + quad - 1;       // u = 3-quad
            if ((unsigned)oy >= 64u) continue;
            float* orow = ob + ((long)c * 64 + oy) * 64;
#pragma unroll
            for (int r = 0; r < 4; ++r) {
                int ox = 2 * ix + r - 1;      // v = 3-r
                if ((unsigned)ox < 64u)
                    atomicAdd(&orow[ox], 0.25f * acc[i][j][r]);
            }
        }
    }
}

extern "C" void kernel_launch(void* const* d_in, const int* in_sizes, int n_in,
                              void* d_out, int out_size, void* d_ws, size_t ws_size,
                              hipStream_t stream) {
    const float* f    = (const float*)d_in[0];
    const float* bsrc = (const float*)d_in[1];
    const float* mask = (const float*)d_in[2];
    float* out = (float*)d_out;
    float* ws = (float*)d_ws;

    // workspace (floats): ~8.9M = 35.7 MB (P slot now unused)
    float* ssq   = ws;                        // 2048
    float* norms = ssq   + 2048;              // 2048
    float* mmb   = norms + 2048;              // 1024
    unsigned short* fH = (unsigned short*)(mmb + 1024);      // 262144 ushorts each
    unsigned short* fL = fH + 262144;
    unsigned short* bH = fL + 262144;
    unsigned short* bL = bH + 262144;
    float* GTa   = (float*)(bL + 262144);     // 2097152 : GT -> attnT(bf16)
    float* C1    = GTa + 2097152;             // 2097152 : S0T
    float* C2    = C1  + 2097152;             // 2097152 : S2T
    unsigned short* Wm = (unsigned short*)(C2 + 2097152);    // 4194304 ushorts
    float* S0T  = C1;
    float* S2T  = C2;
    unsigned short* attnT = (unsigned short*)GTa;  // GT dead after k_s0T

    hipLaunchKernelGGL(k_prep3,     dim3(17920),      dim3(256), 0, stream, f, bsrc, fH, fL, bH, bL, ssq, Wm, out);
    hipLaunchKernelGGL(k_gram,      dim3(16, 16, 3),  dim3(256), 0, stream, fH, fL, bH, bL, GTa, ssq, mask, norms, mmb);
    hipLaunchKernelGGL(k_s0T,       dim3(8192),       dim3(256), 0, stream, GTa, norms, S0T);
    hipLaunchKernelGGL(k_fuse12,    dim3(8192),       dim3(256), 0, stream, S0T, S2T);
    hipLaunchKernelGGL(k_softmaxT,  dim3(512),        dim3(256), 0, stream, S2T, mmb, attnT);
    hipLaunchKernelGGL(k_gemm_mfma, dim3(16, 16, 2),  dim3(256), 0, stream, Wm, attnT, out);
}

// Round 6
// 138.813 us; speedup vs baseline: 5.6427x; 1.1169x over previous
//
#include <hip/hip_runtime.h>
#include <hip/hip_bf16.h>
#include <math.h>

constexpr int HS = 32;      // half spatial (32x32 grids)
constexpr int Lq = 1024;    // HS*HS
constexpr int CN = 128;     // channels
// batches = 2. Inputs fp32 (f, b, mask). Output fp32 (r11-verified).
// R24: gemm identified as 48.8us / MfmaUtil 6% / 4.7M bank-conflict cycles (r23 PMC).
// Changes vs r23:
//  (a) gemm: XOR-swizzled LDS (linear gload_lds dest + pre-swizzled global SOURCE col
//      + swizzled read slot — both-sides rule) -> b128 reads hit all 32 banks (floor).
//  (b) gemm: 2-phase double-buffered K-loop (STAGE(next) before compute, ONE barrier
//      per K-step; compiler's vmcnt(0)-before-barrier drains prefetch) — hides load lat.
//  (c) atomic epilogue REVERTED (r23 regression): P store + separate k_epi2 (r19 code).
// Accumulation/store order identical to r19 => absmax exactly 0.015625.

typedef short bf16x8 __attribute__((ext_vector_type(8)));
typedef float f32x4  __attribute__((ext_vector_type(4)));

__device__ inline unsigned short f2bf(float x) {   // RNE float->bf16 bits
    union { float f; unsigned int u; } c; c.f = x;
    return (unsigned short)((c.u + 0x7FFF + ((c.u >> 16) & 1)) >> 16);
}
__device__ inline float bf2f(unsigned short h) {
    union { unsigned int u; float f; } c; c.u = ((unsigned int)h) << 16;
    return c.f;
}

// async global->LDS, 16B per lane (wave-uniform LDS base + lane*16 layout)
__device__ inline void gload16(const void* g, void* l) {
    __builtin_amdgcn_global_load_lds(
        (const __attribute__((address_space(1))) unsigned int*)g,
        (__attribute__((address_space(3))) unsigned int*)l, 16, 0, 0);
}

// ---------------- merged prep+ssq+wm: one launch, two grid segments ----------------
__global__ __launch_bounds__(256) void k_prep3(const float* __restrict__ f,
                                               const float* __restrict__ bsrc,
                                               unsigned short* __restrict__ fH, unsigned short* __restrict__ fL,
                                               unsigned short* __restrict__ bH, unsigned short* __restrict__ bL,
                                               float* __restrict__ ssq,
                                               unsigned short* __restrict__ Wm) {
    int tx = threadIdx.x;
    if (blockIdx.x < 512) {
        int u = blockIdx.x * 4 + (tx >> 6);  // 0..2047 = bb*1024 + p
        int lane = tx & 63;
        int p = u & (Lq - 1), bb = u >> 10;
        int py = p >> 5, px = p & 31;
        long srcbase = (((long)bb * CN) * 64 + 2 * py) * 64 + 2 * px;
        float s = 0.f;
#pragma unroll
        for (int i = 0; i < 2; ++i) {
            int c = lane + i * 64;
            long src = srcbase + (long)c * 4096;
            float fv = f[src], bv = bsrc[src];
            int o = u * CN + c;
            unsigned short fh = f2bf(fv), bh = f2bf(bv);
            fH[o] = fh; fL[o] = f2bf(fv - bf2f(fh));
            bH[o] = bh; bL[o] = f2bf(bv - bf2f(bh));
            s += bv * bv;
        }
        for (int off = 32; off > 0; off >>= 1) s += __shfl_down(s, off, 64);
        if (lane == 0) ssq[u] = s;
    } else {
        int idx = (blockIdx.x - 512) * 256 + tx;   // 2*2048*1024
        int q  = idx & (Lq - 1);
        int m  = (idx >> 10) & 2047;
        int bb = idx >> 21;
        int c = m >> 4, u = (m >> 2) & 3, v = m & 3;
        int qy = q >> 5, qx = q & 31;
        int y = 2 * qy + u - 1, x = 2 * qx + v - 1;
        float val = 0.f;
        if ((unsigned)y < 64u && (unsigned)x < 64u)
            val = bsrc[(((long)bb * CN + c) * 64 + y) * 64 + x];
        Wm[idx] = f2bf(val);
    }
}

// ---------------- Gram MFMA bf16x2 + merged nm segment (blockIdx.z==2) ----------------
__global__ __launch_bounds__(256) void k_gram(const unsigned short* __restrict__ fH,
                                              const unsigned short* __restrict__ fL,
                                              const unsigned short* __restrict__ bH,
                                              const unsigned short* __restrict__ bL,
                                              float* __restrict__ GT,
                                              const float* __restrict__ ssq, const float* __restrict__ mask,
                                              float* __restrict__ norms, float* __restrict__ mmb) {
    if (blockIdx.z == 2) {                    // ---- nm segment (12 active blocks) ----
        int blk = blockIdx.y * 16 + blockIdx.x;
        if (blk >= 12) return;
        int idx = blk * 256 + threadIdx.x;    // 0..3071
        if (idx < 2048) {
            int q = idx & (Lq - 1);
            int bb = idx >> 10;
            int qy = q >> 5, qx = q & 31;
            float s = 0.1152f;
            for (int dk = -1; dk <= 1; ++dk) {
                int y = qy + dk; if ((unsigned)y >= (unsigned)HS) continue;
                for (int dl = -1; dl <= 1; ++dl) {
                    int x = qx + dl; if ((unsigned)x >= (unsigned)HS) continue;
                    s += ssq[bb * Lq + y * HS + x];
                }
            }
            norms[idx] = sqrtf(s);
        } else if (idx < 3072) {
            int q = idx - 2048;               // 0..1023
            int qy = q >> 5, qx = q & 31;
            float s = 0.f;
            for (int dk = -1; dk <= 1; ++dk) {
                int y = qy + dk; if ((unsigned)y >= (unsigned)HS) continue;
                for (int dl = -1; dl <= 1; ++dl) {
                    int x = qx + dl; if ((unsigned)x >= (unsigned)HS) continue;
                    s += mask[(8 * y) * 256 + 8 * x];
                }
            }
            mmb[q] = (s == 0.0f) ? 1.0f : 0.0f;
        }
        return;
    }
    const long bz = blockIdx.z;
    const unsigned short* AH = fH + bz * 131072;
    const unsigned short* AL = fL + bz * 131072;
    const unsigned short* BH = bH + bz * 131072;
    const unsigned short* BL = bL + bz * 131072;
    float* C = GT + (bz << 20);
    int t = threadIdx.x, w = t >> 6, lane = t & 63, quad = lane >> 4, l16 = lane & 15;
    int wm = blockIdx.x * 64 + (w & 1) * 32;
    int wn = blockIdx.y * 64 + (w >> 1) * 32;
    int ko = quad * 8;
    f32x4 acc[2][2] = {};
#pragma unroll
    for (int k0 = 0; k0 < 128; k0 += 32) {
        bf16x8 ah0 = *(const bf16x8*)&AH[(wm + l16) * 128 + ko + k0];
        bf16x8 ah1 = *(const bf16x8*)&AH[(wm + 16 + l16) * 128 + ko + k0];
        bf16x8 al0 = *(const bf16x8*)&AL[(wm + l16) * 128 + ko + k0];
        bf16x8 al1 = *(const bf16x8*)&AL[(wm + 16 + l16) * 128 + ko + k0];
        bf16x8 bh0 = *(const bf16x8*)&BH[(wn + l16) * 128 + ko + k0];
        bf16x8 bh1 = *(const bf16x8*)&BH[(wn + 16 + l16) * 128 + ko + k0];
        bf16x8 bl0 = *(const bf16x8*)&BL[(wn + l16) * 128 + ko + k0];
        bf16x8 bl1 = *(const bf16x8*)&BL[(wn + 16 + l16) * 128 + ko + k0];
        acc[0][0] = __builtin_amdgcn_mfma_f32_16x16x32_bf16(ah0, bh0, acc[0][0], 0, 0, 0);
        acc[0][1] = __builtin_amdgcn_mfma_f32_16x16x32_bf16(ah0, bh1, acc[0][1], 0, 0, 0);
        acc[1][0] = __builtin_amdgcn_mfma_f32_16x16x32_bf16(ah1, bh0, acc[1][0], 0, 0, 0);
        acc[1][1] = __builtin_amdgcn_mfma_f32_16x16x32_bf16(ah1, bh1, acc[1][1], 0, 0, 0);
        acc[0][0] = __builtin_amdgcn_mfma_f32_16x16x32_bf16(ah0, bl0, acc[0][0], 0, 0, 0);
        acc[0][1] = __builtin_amdgcn_mfma_f32_16x16x32_bf16(ah0, bl1, acc[0][1], 0, 0, 0);
        acc[1][0] = __builtin_amdgcn_mfma_f32_16x16x32_bf16(ah1, bl0, acc[1][0], 0, 0, 0);
        acc[1][1] = __builtin_amdgcn_mfma_f32_16x16x32_bf16(ah1, bl1, acc[1][1], 0, 0, 0);
        acc[0][0] = __builtin_amdgcn_mfma_f32_16x16x32_bf16(al0, bh0, acc[0][0], 0, 0, 0);
        acc[0][1] = __builtin_amdgcn_mfma_f32_16x16x32_bf16(al0, bh1, acc[0][1], 0, 0, 0);
        acc[1][0] = __builtin_amdgcn_mfma_f32_16x16x32_bf16(al1, bh0, acc[1][0], 0, 0, 0);
        acc[1][1] = __builtin_amdgcn_mfma_f32_16x16x32_bf16(al1, bh1, acc[1][1], 0, 0, 0);
    }
#pragma unroll
    for (int i = 0; i < 2; ++i)
#pragma unroll
        for (int j = 0; j < 2; ++j) {
            int mrow = wm + i * 16 + quad * 4;
            int ncol = wn + j * 16 + l16;
#pragma unroll
            for (int r = 0; r < 4; ++r)
                C[(long)(mrow + r) * Lq + ncol] = acc[i][j][r];
        }
}

// ---------------- S0T[p][q] = band9(GT) / norms[q]  (T-layout, r14-verified) ----------------
__global__ __launch_bounds__(256) void k_s0T(const float* __restrict__ GT, const float* __restrict__ norms,
                                             float* __restrict__ S0T) {
    int idx = blockIdx.x * 256 + threadIdx.x;  // 2*1024*1024
    int q  = idx & (Lq - 1);
    int pp = (idx >> 10) & (Lq - 1);
    int bb = idx >> 20;
    int qy = q >> 5, qx = q & 31, py = pp >> 5, px = pp & 31;
    const float* Gb = GT + ((long)bb << 20);
    float s = 0.f;
#pragma unroll
    for (int dk = -1; dk <= 1; ++dk) {
        if ((unsigned)(qy + dk) >= (unsigned)HS || (unsigned)(py + dk) >= (unsigned)HS) continue;
#pragma unroll
        for (int dl = -1; dl <= 1; ++dl) {
            if ((unsigned)(qx + dl) >= (unsigned)HS || (unsigned)(px + dl) >= (unsigned)HS) continue;
            int sft = dk * HS + dl;
            s += Gb[(long)(pp + sft) * Lq + (q + sft)];
        }
    }
    S0T[idx] = s / norms[bb * Lq + q];
}

// ---------------- FUSED fuse1+fuse2 on T layout (r14/r16-verified) ----------------
__global__ __launch_bounds__(256) void k_fuse12(const float* __restrict__ S0, float* __restrict__ S2) {
    int idx = blockIdx.x * 256 + threadIdx.x;   // 2*1024*1024
    int p  = idx & (Lq - 1);
    int q  = (idx >> 10) & (Lq - 1);
    int bb = idx >> 20;
    int hb = q >> 5, wb = q & 31, hf = p >> 5, wf = p & 31;
    int ip = wb * HS + hb, jp = wf * HS + hf;
    const float* S = S0 + (long)bb * Lq * Lq;
    float s = 0.f;
#pragma unroll
    for (int d = -1; d <= 1; ++d) {
        int t = ip + d, r = jp + d;
        if ((unsigned)t < (unsigned)Lq && (unsigned)r < (unsigned)Lq) {
            int q2 = (t & 31) * HS + (t >> 5);
            int p2 = (r & 31) * HS + (r >> 5);
            long base = (long)q2 * Lq + p2;
            float v = S[base];
            if (q2 > 0 && p2 > 0)             v += S[base - (Lq + 1)];
            if (q2 < Lq - 1 && p2 < Lq - 1)   v += S[base + (Lq + 1)];
            s += v;
        }
    }
    S2[idx] = s;
}

// ---------------- row softmax over q on S2T[p][q]; writes attnT bf16 [p][q] (r13-verified) ----------------
__global__ __launch_bounds__(256) void k_softmaxT(const float* __restrict__ S2T, const float* __restrict__ mmb,
                                                  unsigned short* __restrict__ At) {
    int wid = blockIdx.x * 4 + (threadIdx.x >> 6);   // 0..2047
    int lane = threadIdx.x & 63;
    int bb = wid >> 10, p = wid & (Lq - 1);
    const float* row = S2T + ((long)bb << 20) + (long)p * Lq;
    unsigned short* orow = At + ((long)bb << 20) + (long)p * Lq;
    float x[16]; float mx = -1e30f;
#pragma unroll
    for (int i = 0; i < 16; ++i) {
        int q = i * 64 + lane;
        x[i] = row[q] * mmb[q] * 10.0f;
        mx = fmaxf(mx, x[i]);
    }
    for (int off = 32; off > 0; off >>= 1) mx = fmaxf(mx, __shfl_xor(mx, off, 64));
    float e[16]; float s = 0.f;
#pragma unroll
    for (int i = 0; i < 16; ++i) { e[i] = __expf(x[i] - mx); s += e[i]; }
    for (int off = 32; off > 0; off >>= 1) s += __shfl_xor(s, off, 64);
    float inv = 1.0f / s;
#pragma unroll
    for (int i = 0; i < 16; ++i) {
        int q = i * 64 + lane;
        orow[q] = f2bf(e[i] * mmb[q] * inv);
    }
}

// ---------------- MFMA GEMM: 2-phase double-buffer + XOR-swizzled LDS ----------------
// P[m][p] = sum_q Wm[m][q]*attnT[p][q]. BM=128, BN=64, BK=64, grid (16,16,2).
// Swizzle (both-sides): LDS dest linear (gload_lds); global SOURCE col XOR'd by row&7;
// read slot = (ks*4+quad) ^ (l16&7). K order & C store identical to r19 (bit-identical).
__global__ __launch_bounds__(256) void k_gemm_mfma(const unsigned short* __restrict__ WmA,
                                                   const unsigned short* __restrict__ At,
                                                   float* __restrict__ Cm) {
    const long bz = blockIdx.z;
    const unsigned short* A = WmA + bz * (2048L * Lq);
    const unsigned short* B = At  + bz * ((long)Lq * Lq);
    float* C = Cm + bz * (2048L * Lq);
    __shared__ __align__(16) unsigned short As[2][128 * 64];   // 32 KB
    __shared__ __align__(16) unsigned short Bs[2][64 * 64];    // 16 KB
    int t = threadIdx.x;
    int w = t >> 6, lane = t & 63, quad = lane >> 4, l16 = lane & 15;
    int wr = w >> 1, wc = w & 1;             // wave tile: rows wr*64.., cols wc*32..
    int m0 = blockIdx.x * 128, n0 = blockIdx.y * 64;
    int srow  = t >> 3;                       // 0..31: row within a 32-row staging round
    int scolS = ((t & 7) ^ ((t >> 3) & 7)) << 3;  // pre-swizzled global source col (elems)
    int sdst  = t * 8;                        // linear LDS dest (elems) = t*16 bytes
    int xr    = l16 & 7;                      // read-side row XOR key
    f32x4 acc[4][2] = {};

#define STAGE(buf, kk) do {                                                         \
    _Pragma("unroll")                                                               \
    for (int r = 0; r < 4; ++r)  /* A: 128 rows = 4 rounds */                       \
        gload16(A + (long)(m0 + r * 32 + srow) * Lq + (kk) + scolS,                 \
                &As[buf][r * 2048 + sdst]);                                         \
    _Pragma("unroll")                                                               \
    for (int r = 0; r < 2; ++r)  /* B: 64 rows = 2 rounds */                        \
        gload16(B + (long)(n0 + r * 32 + srow) * Lq + (kk) + scolS,                 \
                &Bs[buf][r * 2048 + sdst]);                                         \
} while (0)

    int cur = 0;
    STAGE(0, 0);
    __syncthreads();                          // compiler drains vmcnt(0) before barrier
    for (int k0 = 0; k0 < Lq; k0 += 64) {
        if (k0 + 64 < Lq) STAGE(cur ^ 1, k0 + 64);   // prefetch next tile (overlaps compute)
#pragma unroll
        for (int ks = 0; ks < 2; ++ks) {
            int slot = ((ks * 4 + quad) ^ xr) << 3;  // swizzled 8-elem slot within row
            bf16x8 a[4], b[2];
#pragma unroll
            for (int i = 0; i < 4; ++i)
                a[i] = *(const bf16x8*)&As[cur][(wr * 64 + i * 16 + l16) * 64 + slot];
#pragma unroll
            for (int j = 0; j < 2; ++j)
                b[j] = *(const bf16x8*)&Bs[cur][(wc * 32 + j * 16 + l16) * 64 + slot];
#pragma unroll
            for (int i = 0; i < 4; ++i)
#pragma unroll
                for (int j = 0; j < 2; ++j)
                    acc[i][j] = __builtin_amdgcn_mfma_f32_16x16x32_bf16(a[i], b[j], acc[i][j], 0, 0, 0);
        }
        __syncthreads();                      // drains prefetch vmcnt + protects LDS reuse
        cur ^= 1;
    }
#undef STAGE
#pragma unroll
    for (int i = 0; i < 4; ++i) {
        int mrow = m0 + wr * 64 + i * 16 + quad * 4;
#pragma unroll
        for (int j = 0; j < 2; ++j) {
            int ncol = n0 + wc * 32 + j * 16 + l16;
#pragma unroll
            for (int r = 0; r < 4; ++r)
                C[(long)(mrow + r) * Lq + ncol] = acc[i][j][r];
        }
    }
}

// ---------------- literal conv epilogue: fp32 tap-sum, /4, store fp32 (r11-verified) ----------------
__global__ __launch_bounds__(256) void k_epi2(const float* __restrict__ P, float* __restrict__ out) {
    int idx = blockIdx.x * 256 + threadIdx.x;   // 1048576
    int ox = idx & 63, oy = (idx >> 6) & 63, c = (idx >> 12) & 127, bb = idx >> 19;
    const float* Pb = P + (long)bb * 2048 * Lq;
    float s = 0.f;
#pragma unroll
    for (int u = 0; u < 4; ++u) {
        int t = oy + u - 2;
        if (t & 1) continue;
        int iy = t >> 1;
        if ((unsigned)iy >= (unsigned)HS) continue;
#pragma unroll
        for (int v = 0; v < 4; ++v) {
            int r = ox + v - 2;
            if (r & 1) continue;
            int ix = r >> 1;
            if ((unsigned)ix >= (unsigned)HS) continue;
            s += Pb[(long)((c << 4) + (3 - u) * 4 + (3 - v)) * Lq + (iy << 5) + ix];
        }
    }
    out[idx] = 0.25f * s;
}

extern "C" void kernel_launch(void* const* d_in, const int* in_sizes, int n_in,
                              void* d_out, int out_size, void* d_ws, size_t ws_size,
                              hipStream_t stream) {
    const float* f    = (const float*)d_in[0];
    const float* bsrc = (const float*)d_in[1];
    const float* mask = (const float*)d_in[2];
    float* out = (float*)d_out;
    float* ws = (float*)d_ws;

    // workspace (floats): ~8.9M = 35.7 MB
    float* ssq   = ws;                        // 2048
    float* norms = ssq   + 2048;              // 2048
    float* mmb   = norms + 2048;              // 1024
    unsigned short* fH = (unsigned short*)(mmb + 1024);      // 262144 ushorts each
    unsigned short* fL = fH + 262144;
    unsigned short* bH = fL + 262144;
    unsigned short* bL = bH + 262144;
    float* GTa   = (float*)(bL + 262144);     // 2097152 : GT -> attnT(bf16)
    float* C1    = GTa + 2097152;             // 2097152 : S0T -> P[0:2M]
    float* C2    = C1  + 2097152;             // 2097152 : S2T -> P[2M:4M]
    unsigned short* Wm = (unsigned short*)(C2 + 2097152);    // 4194304 ushorts
    float* S0T  = C1;
    float* S2T  = C2;
    unsigned short* attnT = (unsigned short*)GTa;  // GT dead after k_s0T
    float* P    = C1;      // spans C1+C2; S0T dead after fuse12, S2T dead after softmax

    hipLaunchKernelGGL(k_prep3,     dim3(16896),      dim3(256), 0, stream, f, bsrc, fH, fL, bH, bL, ssq, Wm);
    hipLaunchKernelGGL(k_gram,      dim3(16, 16, 3),  dim3(256), 0, stream, fH, fL, bH, bL, GTa, ssq, mask, norms, mmb);
    hipLaunchKernelGGL(k_s0T,       dim3(8192),       dim3(256), 0, stream, GTa, norms, S0T);
    hipLaunchKernelGGL(k_fuse12,    dim3(8192),       dim3(256), 0, stream, S0T, S2T);
    hipLaunchKernelGGL(k_softmaxT,  dim3(512),        dim3(256), 0, stream, S2T, mmb, attnT);
    hipLaunchKernelGGL(k_gemm_mfma, dim3(16, 16, 2),  dim3(256), 0, stream, Wm, attnT, P);
    hipLaunchKernelGGL(k_epi2,      dim3(4096),       dim3(256), 0, stream, P, out);
}

// Round 7
// 136.628 us; speedup vs baseline: 5.7329x; 1.0160x over previous
//
#include <hip/hip_runtime.h>
#include <hip/hip_bf16.h>
#include <math.h>

constexpr int HS = 32;      // half spatial (32x32 grids)
constexpr int Lq = 1024;    // HS*HS
constexpr int CN = 128;     // channels
// batches = 2. Inputs fp32 (f, b, mask). Output fp32 (r11-verified).
// R25: gemm rewritten for LATENCY (r23 PMC: 420 GB/s eff fetch, 7300 cyc/K-iter => zero MLP):
//  (a) STATIC double buffers As0/As1/Bs0/Bs1, K-loop unrolled x2 — removes runtime-indexed
//      LDS aliasing so the compiler keeps prefetch loads in flight across compute.
//  (b) BM=64,BN=64 -> grid (32,16,2)=1024 blocks = 4 blocks/CU (32KB LDS/block): 2x TLP.
//  (c) XOR swizzle retained (r24-verified). K order identical -> bit-identical C,
//      absmax exactly 0.015625. All other kernels byte-identical to r24 (138.8us best).

typedef short bf16x8 __attribute__((ext_vector_type(8)));
typedef float f32x4  __attribute__((ext_vector_type(4)));

__device__ inline unsigned short f2bf(float x) {   // RNE float->bf16 bits
    union { float f; unsigned int u; } c; c.f = x;
    return (unsigned short)((c.u + 0x7FFF + ((c.u >> 16) & 1)) >> 16);
}
__device__ inline float bf2f(unsigned short h) {
    union { unsigned int u; float f; } c; c.u = ((unsigned int)h) << 16;
    return c.f;
}

// async global->LDS, 16B per lane (wave-uniform LDS base + lane*16 layout)
__device__ inline void gload16(const void* g, void* l) {
    __builtin_amdgcn_global_load_lds(
        (const __attribute__((address_space(1))) unsigned int*)g,
        (__attribute__((address_space(3))) unsigned int*)l, 16, 0, 0);
}

// ---------------- merged prep+ssq+wm: one launch, two grid segments ----------------
__global__ __launch_bounds__(256) void k_prep3(const float* __restrict__ f,
                                               const float* __restrict__ bsrc,
                                               unsigned short* __restrict__ fH, unsigned short* __restrict__ fL,
                                               unsigned short* __restrict__ bH, unsigned short* __restrict__ bL,
                                               float* __restrict__ ssq,
                                               unsigned short* __restrict__ Wm) {
    int tx = threadIdx.x;
    if (blockIdx.x < 512) {
        int u = blockIdx.x * 4 + (tx >> 6);  // 0..2047 = bb*1024 + p
        int lane = tx & 63;
        int p = u & (Lq - 1), bb = u >> 10;
        int py = p >> 5, px = p & 31;
        long srcbase = (((long)bb * CN) * 64 + 2 * py) * 64 + 2 * px;
        float s = 0.f;
#pragma unroll
        for (int i = 0; i < 2; ++i) {
            int c = lane + i * 64;
            long src = srcbase + (long)c * 4096;
            float fv = f[src], bv = bsrc[src];
            int o = u * CN + c;
            unsigned short fh = f2bf(fv), bh = f2bf(bv);
            fH[o] = fh; fL[o] = f2bf(fv - bf2f(fh));
            bH[o] = bh; bL[o] = f2bf(bv - bf2f(bh));
            s += bv * bv;
        }
        for (int off = 32; off > 0; off >>= 1) s += __shfl_down(s, off, 64);
        if (lane == 0) ssq[u] = s;
    } else {
        int idx = (blockIdx.x - 512) * 256 + tx;   // 2*2048*1024
        int q  = idx & (Lq - 1);
        int m  = (idx >> 10) & 2047;
        int bb = idx >> 21;
        int c = m >> 4, u = (m >> 2) & 3, v = m & 3;
        int qy = q >> 5, qx = q & 31;
        int y = 2 * qy + u - 1, x = 2 * qx + v - 1;
        float val = 0.f;
        if ((unsigned)y < 64u && (unsigned)x < 64u)
            val = bsrc[(((long)bb * CN + c) * 64 + y) * 64 + x];
        Wm[idx] = f2bf(val);
    }
}

// ---------------- Gram MFMA bf16x2 + merged nm segment (blockIdx.z==2) ----------------
__global__ __launch_bounds__(256) void k_gram(const unsigned short* __restrict__ fH,
                                              const unsigned short* __restrict__ fL,
                                              const unsigned short* __restrict__ bH,
                                              const unsigned short* __restrict__ bL,
                                              float* __restrict__ GT,
                                              const float* __restrict__ ssq, const float* __restrict__ mask,
                                              float* __restrict__ norms, float* __restrict__ mmb) {
    if (blockIdx.z == 2) {                    // ---- nm segment (12 active blocks) ----
        int blk = blockIdx.y * 16 + blockIdx.x;
        if (blk >= 12) return;
        int idx = blk * 256 + threadIdx.x;    // 0..3071
        if (idx < 2048) {
            int q = idx & (Lq - 1);
            int bb = idx >> 10;
            int qy = q >> 5, qx = q & 31;
            float s = 0.1152f;
            for (int dk = -1; dk <= 1; ++dk) {
                int y = qy + dk; if ((unsigned)y >= (unsigned)HS) continue;
                for (int dl = -1; dl <= 1; ++dl) {
                    int x = qx + dl; if ((unsigned)x >= (unsigned)HS) continue;
                    s += ssq[bb * Lq + y * HS + x];
                }
            }
            norms[idx] = sqrtf(s);
        } else if (idx < 3072) {
            int q = idx - 2048;               // 0..1023
            int qy = q >> 5, qx = q & 31;
            float s = 0.f;
            for (int dk = -1; dk <= 1; ++dk) {
                int y = qy + dk; if ((unsigned)y >= (unsigned)HS) continue;
                for (int dl = -1; dl <= 1; ++dl) {
                    int x = qx + dl; if ((unsigned)x >= (unsigned)HS) continue;
                    s += mask[(8 * y) * 256 + 8 * x];
                }
            }
            mmb[q] = (s == 0.0f) ? 1.0f : 0.0f;
        }
        return;
    }
    const long bz = blockIdx.z;
    const unsigned short* AH = fH + bz * 131072;
    const unsigned short* AL = fL + bz * 131072;
    const unsigned short* BH = bH + bz * 131072;
    const unsigned short* BL = bL + bz * 131072;
    float* C = GT + (bz << 20);
    int t = threadIdx.x, w = t >> 6, lane = t & 63, quad = lane >> 4, l16 = lane & 15;
    int wm = blockIdx.x * 64 + (w & 1) * 32;
    int wn = blockIdx.y * 64 + (w >> 1) * 32;
    int ko = quad * 8;
    f32x4 acc[2][2] = {};
#pragma unroll
    for (int k0 = 0; k0 < 128; k0 += 32) {
        bf16x8 ah0 = *(const bf16x8*)&AH[(wm + l16) * 128 + ko + k0];
        bf16x8 ah1 = *(const bf16x8*)&AH[(wm + 16 + l16) * 128 + ko + k0];
        bf16x8 al0 = *(const bf16x8*)&AL[(wm + l16) * 128 + ko + k0];
        bf16x8 al1 = *(const bf16x8*)&AL[(wm + 16 + l16) * 128 + ko + k0];
        bf16x8 bh0 = *(const bf16x8*)&BH[(wn + l16) * 128 + ko + k0];
        bf16x8 bh1 = *(const bf16x8*)&BH[(wn + 16 + l16) * 128 + ko + k0];
        bf16x8 bl0 = *(const bf16x8*)&BL[(wn + l16) * 128 + ko + k0];
        bf16x8 bl1 = *(const bf16x8*)&BL[(wn + 16 + l16) * 128 + ko + k0];
        acc[0][0] = __builtin_amdgcn_mfma_f32_16x16x32_bf16(ah0, bh0, acc[0][0], 0, 0, 0);
        acc[0][1] = __builtin_amdgcn_mfma_f32_16x16x32_bf16(ah0, bh1, acc[0][1], 0, 0, 0);
        acc[1][0] = __builtin_amdgcn_mfma_f32_16x16x32_bf16(ah1, bh0, acc[1][0], 0, 0, 0);
        acc[1][1] = __builtin_amdgcn_mfma_f32_16x16x32_bf16(ah1, bh1, acc[1][1], 0, 0, 0);
        acc[0][0] = __builtin_amdgcn_mfma_f32_16x16x32_bf16(ah0, bl0, acc[0][0], 0, 0, 0);
        acc[0][1] = __builtin_amdgcn_mfma_f32_16x16x32_bf16(ah0, bl1, acc[0][1], 0, 0, 0);
        acc[1][0] = __builtin_amdgcn_mfma_f32_16x16x32_bf16(ah1, bl0, acc[1][0], 0, 0, 0);
        acc[1][1] = __builtin_amdgcn_mfma_f32_16x16x32_bf16(ah1, bl1, acc[1][1], 0, 0, 0);
        acc[0][0] = __builtin_amdgcn_mfma_f32_16x16x32_bf16(al0, bh0, acc[0][0], 0, 0, 0);
        acc[0][1] = __builtin_amdgcn_mfma_f32_16x16x32_bf16(al0, bh1, acc[0][1], 0, 0, 0);
        acc[1][0] = __builtin_amdgcn_mfma_f32_16x16x32_bf16(al1, bh0, acc[1][0], 0, 0, 0);
        acc[1][1] = __builtin_amdgcn_mfma_f32_16x16x32_bf16(al1, bh1, acc[1][1], 0, 0, 0);
    }
#pragma unroll
    for (int i = 0; i < 2; ++i)
#pragma unroll
        for (int j = 0; j < 2; ++j) {
            int mrow = wm + i * 16 + quad * 4;
            int ncol = wn + j * 16 + l16;
#pragma unroll
            for (int r = 0; r < 4; ++r)
                C[(long)(mrow + r) * Lq + ncol] = acc[i][j][r];
        }
}

// ---------------- S0T[p][q] = band9(GT) / norms[q]  (T-layout, r14-verified) ----------------
__global__ __launch_bounds__(256) void k_s0T(const float* __restrict__ GT, const float* __restrict__ norms,
                                             float* __restrict__ S0T) {
    int idx = blockIdx.x * 256 + threadIdx.x;  // 2*1024*1024
    int q  = idx & (Lq - 1);
    int pp = (idx >> 10) & (Lq - 1);
    int bb = idx >> 20;
    int qy = q >> 5, qx = q & 31, py = pp >> 5, px = pp & 31;
    const float* Gb = GT + ((long)bb << 20);
    float s = 0.f;
#pragma unroll
    for (int dk = -1; dk <= 1; ++dk) {
        if ((unsigned)(qy + dk) >= (unsigned)HS || (unsigned)(py + dk) >= (unsigned)HS) continue;
#pragma unroll
        for (int dl = -1; dl <= 1; ++dl) {
            if ((unsigned)(qx + dl) >= (unsigned)HS || (unsigned)(px + dl) >= (unsigned)HS) continue;
            int sft = dk * HS + dl;
            s += Gb[(long)(pp + sft) * Lq + (q + sft)];
        }
    }
    S0T[idx] = s / norms[bb * Lq + q];
}

// ---------------- FUSED fuse1+fuse2 on T layout (r14/r16-verified) ----------------
__global__ __launch_bounds__(256) void k_fuse12(const float* __restrict__ S0, float* __restrict__ S2) {
    int idx = blockIdx.x * 256 + threadIdx.x;   // 2*1024*1024
    int p  = idx & (Lq - 1);
    int q  = (idx >> 10) & (Lq - 1);
    int bb = idx >> 20;
    int hb = q >> 5, wb = q & 31, hf = p >> 5, wf = p & 31;
    int ip = wb * HS + hb, jp = wf * HS + hf;
    const float* S = S0 + (long)bb * Lq * Lq;
    float s = 0.f;
#pragma unroll
    for (int d = -1; d <= 1; ++d) {
        int t = ip + d, r = jp + d;
        if ((unsigned)t < (unsigned)Lq && (unsigned)r < (unsigned)Lq) {
            int q2 = (t & 31) * HS + (t >> 5);
            int p2 = (r & 31) * HS + (r >> 5);
            long base = (long)q2 * Lq + p2;
            float v = S[base];
            if (q2 > 0 && p2 > 0)             v += S[base - (Lq + 1)];
            if (q2 < Lq - 1 && p2 < Lq - 1)   v += S[base + (Lq + 1)];
            s += v;
        }
    }
    S2[idx] = s;
}

// ---------------- row softmax over q on S2T[p][q]; writes attnT bf16 [p][q] (r13-verified) ----------------
__global__ __launch_bounds__(256) void k_softmaxT(const float* __restrict__ S2T, const float* __restrict__ mmb,
                                                  unsigned short* __restrict__ At) {
    int wid = blockIdx.x * 4 + (threadIdx.x >> 6);   // 0..2047
    int lane = threadIdx.x & 63;
    int bb = wid >> 10, p = wid & (Lq - 1);
    const float* row = S2T + ((long)bb << 20) + (long)p * Lq;
    unsigned short* orow = At + ((long)bb << 20) + (long)p * Lq;
    float x[16]; float mx = -1e30f;
#pragma unroll
    for (int i = 0; i < 16; ++i) {
        int q = i * 64 + lane;
        x[i] = row[q] * mmb[q] * 10.0f;
        mx = fmaxf(mx, x[i]);
    }
    for (int off = 32; off > 0; off >>= 1) mx = fmaxf(mx, __shfl_xor(mx, off, 64));
    float e[16]; float s = 0.f;
#pragma unroll
    for (int i = 0; i < 16; ++i) { e[i] = __expf(x[i] - mx); s += e[i]; }
    for (int off = 32; off > 0; off >>= 1) s += __shfl_xor(s, off, 64);
    float inv = 1.0f / s;
#pragma unroll
    for (int i = 0; i < 16; ++i) {
        int q = i * 64 + lane;
        orow[q] = f2bf(e[i] * mmb[q] * inv);
    }
}

// ---------------- MFMA GEMM: 64x64 tile, STATIC dbuf prefetch, XOR-swizzled LDS ----------------
// P[m][p] = sum_q Wm[m][q]*attnT[p][q]. BM=64, BN=64, BK=64, grid (32,16,2) = 4 blocks/CU.
// Static As0/As1/Bs0/Bs1 so compiler proves prefetch-vs-read independence (keeps loads
// in flight across compute). K order & per-output accumulation identical to r24.
__global__ __launch_bounds__(256) void k_gemm_mfma(const unsigned short* __restrict__ WmA,
                                                   const unsigned short* __restrict__ At,
                                                   float* __restrict__ Cm) {
    const long bz = blockIdx.z;
    const unsigned short* A = WmA + bz * (2048L * Lq);
    const unsigned short* B = At  + bz * ((long)Lq * Lq);
    float* C = Cm + bz * (2048L * Lq);
    __shared__ __align__(16) unsigned short As0[64 * 64], As1[64 * 64];  // 8 KB each
    __shared__ __align__(16) unsigned short Bs0[64 * 64], Bs1[64 * 64];  // 32 KB total
    int t = threadIdx.x;
    int w = t >> 6, lane = t & 63, quad = lane >> 4, l16 = lane & 15;
    int wr = w >> 1, wc = w & 1;             // 2x2 wave grid; wave tile 32x32
    int m0 = blockIdx.x * 64, n0 = blockIdx.y * 64;
    int srow  = t >> 3;                       // 0..31: row within a 32-row staging round
    int scolS = ((t & 7) ^ ((t >> 3) & 7)) << 3;  // pre-swizzled global source col (elems)
    int sdst  = t * 8;                        // linear LDS dest (elems) = t*16 bytes
    int xr    = l16 & 7;                      // read-side row XOR key
    f32x4 acc[2][2] = {};

#define STG(AS, BS, kk) do {                                                        \
    _Pragma("unroll")                                                               \
    for (int r = 0; r < 2; ++r)  /* A: 64 rows = 2 rounds */                        \
        gload16(A + (long)(m0 + r * 32 + srow) * Lq + (kk) + scolS,                 \
                &AS[r * 2048 + sdst]);                                              \
    _Pragma("unroll")                                                               \
    for (int r = 0; r < 2; ++r)  /* B: 64 rows = 2 rounds */                        \
        gload16(B + (long)(n0 + r * 32 + srow) * Lq + (kk) + scolS,                 \
                &BS[r * 2048 + sdst]);                                              \
} while (0)

#define CMP(AS, BS) do {                                                            \
    _Pragma("unroll")                                                               \
    for (int ks = 0; ks < 2; ++ks) {                                                \
        int slot = ((ks * 4 + quad) ^ xr) << 3;                                     \
        bf16x8 a0 = *(const bf16x8*)&AS[(wr * 32 +      l16) * 64 + slot];          \
        bf16x8 a1 = *(const bf16x8*)&AS[(wr * 32 + 16 + l16) * 64 + slot];          \
        bf16x8 b0 = *(const bf16x8*)&BS[(wc * 32 +      l16) * 64 + slot];          \
        bf16x8 b1 = *(const bf16x8*)&BS[(wc * 32 + 16 + l16) * 64 + slot];          \
        acc[0][0] = __builtin_amdgcn_mfma_f32_16x16x32_bf16(a0, b0, acc[0][0], 0, 0, 0); \
        acc[0][1] = __builtin_amdgcn_mfma_f32_16x16x32_bf16(a0, b1, acc[0][1], 0, 0, 0); \
        acc[1][0] = __builtin_amdgcn_mfma_f32_16x16x32_bf16(a1, b0, acc[1][0], 0, 0, 0); \
        acc[1][1] = __builtin_amdgcn_mfma_f32_16x16x32_bf16(a1, b1, acc[1][1], 0, 0, 0); \
    }                                                                               \
} while (0)

    STG(As0, Bs0, 0);
    __syncthreads();                          // drain initial stage
    for (int k0 = 0; k0 < Lq; k0 += 128) {
        STG(As1, Bs1, k0 + 64);               // prefetch next half (in flight over CMP)
        CMP(As0, Bs0);
        __syncthreads();                      // drains prefetch; protects As0 reuse
        if (k0 + 128 < Lq) STG(As0, Bs0, k0 + 128);
        CMP(As1, Bs1);
        __syncthreads();
    }
#undef STG
#undef CMP
#pragma unroll
    for (int i = 0; i < 2; ++i) {
        int mrow = m0 + wr * 32 + i * 16 + quad * 4;
#pragma unroll
        for (int j = 0; j < 2; ++j) {
            int ncol = n0 + wc * 32 + j * 16 + l16;
#pragma unroll
            for (int r = 0; r < 4; ++r)
                C[(long)(mrow + r) * Lq + ncol] = acc[i][j][r];
        }
    }
}

// ---------------- literal conv epilogue: fp32 tap-sum, /4, store fp32 (r11-verified) ----------------
__global__ __launch_bounds__(256) void k_epi2(const float* __restrict__ P, float* __restrict__ out) {
    int idx = blockIdx.x * 256 + threadIdx.x;   // 1048576
    int ox = idx & 63, oy = (idx >> 6) & 63, c = (idx >> 12) & 127, bb = idx >> 19;
    const float* Pb = P + (long)bb * 2048 * Lq;
    float s = 0.f;
#pragma unroll
    for (int u = 0; u < 4; ++u) {
        int t = oy + u - 2;
        if (t & 1) continue;
        int iy = t >> 1;
        if ((unsigned)iy >= (unsigned)HS) continue;
#pragma unroll
        for (int v = 0; v < 4; ++v) {
            int r = ox + v - 2;
            if (r & 1) continue;
            int ix = r >> 1;
            if ((unsigned)ix >= (unsigned)HS) continue;
            s += Pb[(long)((c << 4) + (3 - u) * 4 + (3 - v)) * Lq + (iy << 5) + ix];
        }
    }
    out[idx] = 0.25f * s;
}

extern "C" void kernel_launch(void* const* d_in, const int* in_sizes, int n_in,
                              void* d_out, int out_size, void* d_ws, size_t ws_size,
                              hipStream_t stream) {
    const float* f    = (const float*)d_in[0];
    const float* bsrc = (const float*)d_in[1];
    const float* mask = (const float*)d_in[2];
    float* out = (float*)d_out;
    float* ws = (float*)d_ws;

    // workspace (floats): ~8.9M = 35.7 MB
    float* ssq   = ws;                        // 2048
    float* norms = ssq   + 2048;              // 2048
    float* mmb   = norms + 2048;              // 1024
    unsigned short* fH = (unsigned short*)(mmb + 1024);      // 262144 ushorts each
    unsigned short* fL = fH + 262144;
    unsigned short* bH = fL + 262144;
    unsigned short* bL = bH + 262144;
    float* GTa   = (float*)(bL + 262144);     // 2097152 : GT -> attnT(bf16)
    float* C1    = GTa + 2097152;             // 2097152 : S0T -> P[0:2M]
    float* C2    = C1  + 2097152;             // 2097152 : S2T -> P[2M:4M]
    unsigned short* Wm = (unsigned short*)(C2 + 2097152);    // 4194304 ushorts
    float* S0T  = C1;
    float* S2T  = C2;
    unsigned short* attnT = (unsigned short*)GTa;  // GT dead after k_s0T
    float* P    = C1;      // spans C1+C2; S0T dead after fuse12, S2T dead after softmax

    hipLaunchKernelGGL(k_prep3,     dim3(16896),      dim3(256), 0, stream, f, bsrc, fH, fL, bH, bL, ssq, Wm);
    hipLaunchKernelGGL(k_gram,      dim3(16, 16, 3),  dim3(256), 0, stream, fH, fL, bH, bL, GTa, ssq, mask, norms, mmb);
    hipLaunchKernelGGL(k_s0T,       dim3(8192),       dim3(256), 0, stream, GTa, norms, S0T);
    hipLaunchKernelGGL(k_fuse12,    dim3(8192),       dim3(256), 0, stream, S0T, S2T);
    hipLaunchKernelGGL(k_softmaxT,  dim3(512),        dim3(256), 0, stream, S2T, mmb, attnT);
    hipLaunchKernelGGL(k_gemm_mfma, dim3(32, 16, 2),  dim3(256), 0, stream, Wm, attnT, P);
    hipLaunchKernelGGL(k_epi2,      dim3(4096),       dim3(256), 0, stream, P, out);
}

// Round 9
// 136.352 us; speedup vs baseline: 5.7445x; 1.0020x over previous
//
#include <hip/hip_runtime.h>
#include <hip/hip_bf16.h>
#include <math.h>

constexpr int HS = 32;      // half spatial (32x32 grids)
constexpr int Lq = 1024;    // HS*HS
constexpr int CN = 128;     // channels
// batches = 2. Inputs fp32 (f, b, mask). Output fp32 (r11-verified).
// R27 == R26 resubmit (bench died with "container failed twice" — no verdict; kernel
// re-audited for hang risk: uniform barriers, fixed trip count, LDS 32KB ok).
// R26: gemm K-loop -> counted-vmcnt pipeline (catalog T4/m218, m201 template):
// 2 K-tiles in flight; per tile: s_waitcnt vmcnt(4) (never 0 mid-loop) + RAW s_barrier
// (no compiler vmcnt(0) drain) -> CMP -> s_barrier -> re-STAGE 2 tiles ahead.
// Read/compute order unchanged -> bit-identical C, absmax exactly 0.015625.
// All else byte-identical to r25 (136.6 best).

typedef short bf16x8 __attribute__((ext_vector_type(8)));
typedef float f32x4  __attribute__((ext_vector_type(4)));

__device__ inline unsigned short f2bf(float x) {   // RNE float->bf16 bits
    union { float f; unsigned int u; } c; c.f = x;
    return (unsigned short)((c.u + 0x7FFF + ((c.u >> 16) & 1)) >> 16);
}
__device__ inline float bf2f(unsigned short h) {
    union { unsigned int u; float f; } c; c.u = ((unsigned int)h) << 16;
    return c.f;
}

// async global->LDS, 16B per lane (wave-uniform LDS base + lane*16 layout)
__device__ inline void gload16(const void* g, void* l) {
    __builtin_amdgcn_global_load_lds(
        (const __attribute__((address_space(1))) unsigned int*)g,
        (__attribute__((address_space(3))) unsigned int*)l, 16, 0, 0);
}

// ---------------- merged prep+ssq+wm: one launch, two grid segments ----------------
__global__ __launch_bounds__(256) void k_prep3(const float* __restrict__ f,
                                               const float* __restrict__ bsrc,
                                               unsigned short* __restrict__ fH, unsigned short* __restrict__ fL,
                                               unsigned short* __restrict__ bH, unsigned short* __restrict__ bL,
                                               float* __restrict__ ssq,
                                               unsigned short* __restrict__ Wm) {
    int tx = threadIdx.x;
    if (blockIdx.x < 512) {
        int u = blockIdx.x * 4 + (tx >> 6);  // 0..2047 = bb*1024 + p
        int lane = tx & 63;
        int p = u & (Lq - 1), bb = u >> 10;
        int py = p >> 5, px = p & 31;
        long srcbase = (((long)bb * CN) * 64 + 2 * py) * 64 + 2 * px;
        float s = 0.f;
#pragma unroll
        for (int i = 0; i < 2; ++i) {
            int c = lane + i * 64;
            long src = srcbase + (long)c * 4096;
            float fv = f[src], bv = bsrc[src];
            int o = u * CN + c;
            unsigned short fh = f2bf(fv), bh = f2bf(bv);
            fH[o] = fh; fL[o] = f2bf(fv - bf2f(fh));
            bH[o] = bh; bL[o] = f2bf(bv - bf2f(bh));
            s += bv * bv;
        }
        for (int off = 32; off > 0; off >>= 1) s += __shfl_down(s, off, 64);
        if (lane == 0) ssq[u] = s;
    } else {
        int idx = (blockIdx.x - 512) * 256 + tx;   // 2*2048*1024
        int q  = idx & (Lq - 1);
        int m  = (idx >> 10) & 2047;
        int bb = idx >> 21;
        int c = m >> 4, u = (m >> 2) & 3, v = m & 3;
        int qy = q >> 5, qx = q & 31;
        int y = 2 * qy + u - 1, x = 2 * qx + v - 1;
        float val = 0.f;
        if ((unsigned)y < 64u && (unsigned)x < 64u)
            val = bsrc[(((long)bb * CN + c) * 64 + y) * 64 + x];
        Wm[idx] = f2bf(val);
    }
}

// ---------------- Gram MFMA bf16x2 + merged nm segment (blockIdx.z==2) ----------------
__global__ __launch_bounds__(256) void k_gram(const unsigned short* __restrict__ fH,
                                              const unsigned short* __restrict__ fL,
                                              const unsigned short* __restrict__ bH,
                                              const unsigned short* __restrict__ bL,
                                              float* __restrict__ GT,
                                              const float* __restrict__ ssq, const float* __restrict__ mask,
                                              float* __restrict__ norms, float* __restrict__ mmb) {
    if (blockIdx.z == 2) {                    // ---- nm segment (12 active blocks) ----
        int blk = blockIdx.y * 16 + blockIdx.x;
        if (blk >= 12) return;
        int idx = blk * 256 + threadIdx.x;    // 0..3071
        if (idx < 2048) {
            int q = idx & (Lq - 1);
            int bb = idx >> 10;
            int qy = q >> 5, qx = q & 31;
            float s = 0.1152f;
            for (int dk = -1; dk <= 1; ++dk) {
                int y = qy + dk; if ((unsigned)y >= (unsigned)HS) continue;
                for (int dl = -1; dl <= 1; ++dl) {
                    int x = qx + dl; if ((unsigned)x >= (unsigned)HS) continue;
                    s += ssq[bb * Lq + y * HS + x];
                }
            }
            norms[idx] = sqrtf(s);
        } else if (idx < 3072) {
            int q = idx - 2048;               // 0..1023
            int qy = q >> 5, qx = q & 31;
            float s = 0.f;
            for (int dk = -1; dk <= 1; ++dk) {
                int y = qy + dk; if ((unsigned)y >= (unsigned)HS) continue;
                for (int dl = -1; dl <= 1; ++dl) {
                    int x = qx + dl; if ((unsigned)x >= (unsigned)HS) continue;
                    s += mask[(8 * y) * 256 + 8 * x];
                }
            }
            mmb[q] = (s == 0.0f) ? 1.0f : 0.0f;
        }
        return;
    }
    const long bz = blockIdx.z;
    const unsigned short* AH = fH + bz * 131072;
    const unsigned short* AL = fL + bz * 131072;
    const unsigned short* BH = bH + bz * 131072;
    const unsigned short* BL = bL + bz * 131072;
    float* C = GT + (bz << 20);
    int t = threadIdx.x, w = t >> 6, lane = t & 63, quad = lane >> 4, l16 = lane & 15;
    int wm = blockIdx.x * 64 + (w & 1) * 32;
    int wn = blockIdx.y * 64 + (w >> 1) * 32;
    int ko = quad * 8;
    f32x4 acc[2][2] = {};
#pragma unroll
    for (int k0 = 0; k0 < 128; k0 += 32) {
        bf16x8 ah0 = *(const bf16x8*)&AH[(wm + l16) * 128 + ko + k0];
        bf16x8 ah1 = *(const bf16x8*)&AH[(wm + 16 + l16) * 128 + ko + k0];
        bf16x8 al0 = *(const bf16x8*)&AL[(wm + l16) * 128 + ko + k0];
        bf16x8 al1 = *(const bf16x8*)&AL[(wm + 16 + l16) * 128 + ko + k0];
        bf16x8 bh0 = *(const bf16x8*)&BH[(wn + l16) * 128 + ko + k0];
        bf16x8 bh1 = *(const bf16x8*)&BH[(wn + 16 + l16) * 128 + ko + k0];
        bf16x8 bl0 = *(const bf16x8*)&BL[(wn + l16) * 128 + ko + k0];
        bf16x8 bl1 = *(const bf16x8*)&BL[(wn + 16 + l16) * 128 + ko + k0];
        acc[0][0] = __builtin_amdgcn_mfma_f32_16x16x32_bf16(ah0, bh0, acc[0][0], 0, 0, 0);
        acc[0][1] = __builtin_amdgcn_mfma_f32_16x16x32_bf16(ah0, bh1, acc[0][1], 0, 0, 0);
        acc[1][0] = __builtin_amdgcn_mfma_f32_16x16x32_bf16(ah1, bh0, acc[1][0], 0, 0, 0);
        acc[1][1] = __builtin_amdgcn_mfma_f32_16x16x32_bf16(ah1, bh1, acc[1][1], 0, 0, 0);
        acc[0][0] = __builtin_amdgcn_mfma_f32_16x16x32_bf16(ah0, bl0, acc[0][0], 0, 0, 0);
        acc[0][1] = __builtin_amdgcn_mfma_f32_16x16x32_bf16(ah0, bl1, acc[0][1], 0, 0, 0);
        acc[1][0] = __builtin_amdgcn_mfma_f32_16x16x32_bf16(ah1, bl0, acc[1][0], 0, 0, 0);
        acc[1][1] = __builtin_amdgcn_mfma_f32_16x16x32_bf16(ah1, bl1, acc[1][1], 0, 0, 0);
        acc[0][0] = __builtin_amdgcn_mfma_f32_16x16x32_bf16(al0, bh0, acc[0][0], 0, 0, 0);
        acc[0][1] = __builtin_amdgcn_mfma_f32_16x16x32_bf16(al0, bh1, acc[0][1], 0, 0, 0);
        acc[1][0] = __builtin_amdgcn_mfma_f32_16x16x32_bf16(al1, bh0, acc[1][0], 0, 0, 0);
        acc[1][1] = __builtin_amdgcn_mfma_f32_16x16x32_bf16(al1, bh1, acc[1][1], 0, 0, 0);
    }
#pragma unroll
    for (int i = 0; i < 2; ++i)
#pragma unroll
        for (int j = 0; j < 2; ++j) {
            int mrow = wm + i * 16 + quad * 4;
            int ncol = wn + j * 16 + l16;
#pragma unroll
            for (int r = 0; r < 4; ++r)
                C[(long)(mrow + r) * Lq + ncol] = acc[i][j][r];
        }
}

// ---------------- S0T[p][q] = band9(GT) / norms[q]  (T-layout, r14-verified) ----------------
__global__ __launch_bounds__(256) void k_s0T(const float* __restrict__ GT, const float* __restrict__ norms,
                                             float* __restrict__ S0T) {
    int idx = blockIdx.x * 256 + threadIdx.x;  // 2*1024*1024
    int q  = idx & (Lq - 1);
    int pp = (idx >> 10) & (Lq - 1);
    int bb = idx >> 20;
    int qy = q >> 5, qx = q & 31, py = pp >> 5, px = pp & 31;
    const float* Gb = GT + ((long)bb << 20);
    float s = 0.f;
#pragma unroll
    for (int dk = -1; dk <= 1; ++dk) {
        if ((unsigned)(qy + dk) >= (unsigned)HS || (unsigned)(py + dk) >= (unsigned)HS) continue;
#pragma unroll
        for (int dl = -1; dl <= 1; ++dl) {
            if ((unsigned)(qx + dl) >= (unsigned)HS || (unsigned)(px + dl) >= (unsigned)HS) continue;
            int sft = dk * HS + dl;
            s += Gb[(long)(pp + sft) * Lq + (q + sft)];
        }
    }
    S0T[idx] = s / norms[bb * Lq + q];
}

// ---------------- FUSED fuse1+fuse2 on T layout (r14/r16-verified) ----------------
__global__ __launch_bounds__(256) void k_fuse12(const float* __restrict__ S0, float* __restrict__ S2) {
    int idx = blockIdx.x * 256 + threadIdx.x;   // 2*1024*1024
    int p  = idx & (Lq - 1);
    int q  = (idx >> 10) & (Lq - 1);
    int bb = idx >> 20;
    int hb = q >> 5, wb = q & 31, hf = p >> 5, wf = p & 31;
    int ip = wb * HS + hb, jp = wf * HS + hf;
    const float* S = S0 + (long)bb * Lq * Lq;
    float s = 0.f;
#pragma unroll
    for (int d = -1; d <= 1; ++d) {
        int t = ip + d, r = jp + d;
        if ((unsigned)t < (unsigned)Lq && (unsigned)r < (unsigned)Lq) {
            int q2 = (t & 31) * HS + (t >> 5);
            int p2 = (r & 31) * HS + (r >> 5);
            long base = (long)q2 * Lq + p2;
            float v = S[base];
            if (q2 > 0 && p2 > 0)             v += S[base - (Lq + 1)];
            if (q2 < Lq - 1 && p2 < Lq - 1)   v += S[base + (Lq + 1)];
            s += v;
        }
    }
    S2[idx] = s;
}

// ---------------- row softmax over q on S2T[p][q]; writes attnT bf16 [p][q] (r13-verified) ----------------
__global__ __launch_bounds__(256) void k_softmaxT(const float* __restrict__ S2T, const float* __restrict__ mmb,
                                                  unsigned short* __restrict__ At) {
    int wid = blockIdx.x * 4 + (threadIdx.x >> 6);   // 0..2047
    int lane = threadIdx.x & 63;
    int bb = wid >> 10, p = wid & (Lq - 1);
    const float* row = S2T + ((long)bb << 20) + (long)p * Lq;
    unsigned short* orow = At + ((long)bb << 20) + (long)p * Lq;
    float x[16]; float mx = -1e30f;
#pragma unroll
    for (int i = 0; i < 16; ++i) {
        int q = i * 64 + lane;
        x[i] = row[q] * mmb[q] * 10.0f;
        mx = fmaxf(mx, x[i]);
    }
    for (int off = 32; off > 0; off >>= 1) mx = fmaxf(mx, __shfl_xor(mx, off, 64));
    float e[16]; float s = 0.f;
#pragma unroll
    for (int i = 0; i < 16; ++i) { e[i] = __expf(x[i] - mx); s += e[i]; }
    for (int off = 32; off > 0; off >>= 1) s += __shfl_xor(s, off, 64);
    float inv = 1.0f / s;
#pragma unroll
    for (int i = 0; i < 16; ++i) {
        int q = i * 64 + lane;
        orow[q] = f2bf(e[i] * mmb[q] * inv);
    }
}

// ---------------- MFMA GEMM: 64x64 tile, counted-vmcnt 2-deep pipeline, XOR swizzle ----------------
// P[m][p] = sum_q Wm[m][q]*attnT[p][q]. BM=64, BN=64, BK=64, grid (32,16,2) = 4 blocks/CU.
// Discipline: raw s_barrier (no compiler vmcnt0 drain) + asm s_waitcnt vmcnt(4) —
// newest tile's 4 loads stay in flight across the next CMP + 2 barriers (T4 recipe).
__global__ __launch_bounds__(256) void k_gemm_mfma(const unsigned short* __restrict__ WmA,
                                                   const unsigned short* __restrict__ At,
                                                   float* __restrict__ Cm) {
    const long bz = blockIdx.z;
    const unsigned short* A = WmA + bz * (2048L * Lq);
    const unsigned short* B = At  + bz * ((long)Lq * Lq);
    float* C = Cm + bz * (2048L * Lq);
    __shared__ __align__(16) unsigned short As0[64 * 64], As1[64 * 64];  // 8 KB each
    __shared__ __align__(16) unsigned short Bs0[64 * 64], Bs1[64 * 64];  // 32 KB total
    int t = threadIdx.x;
    int w = t >> 6, lane = t & 63, quad = lane >> 4, l16 = lane & 15;
    int wr = w >> 1, wc = w & 1;             // 2x2 wave grid; wave tile 32x32
    int m0 = blockIdx.x * 64, n0 = blockIdx.y * 64;
    int srow  = t >> 3;                       // 0..31: row within a 32-row staging round
    int scolS = ((t & 7) ^ ((t >> 3) & 7)) << 3;  // pre-swizzled global source col (elems)
    int sdst  = t * 8;                        // linear LDS dest (elems) = t*16 bytes
    int xr    = l16 & 7;                      // read-side row XOR key
    f32x4 acc[2][2] = {};

#define STG(AS, BS, kk) do {                                                        \
    _Pragma("unroll")                                                               \
    for (int r = 0; r < 2; ++r)  /* A: 64 rows = 2 rounds */                        \
        gload16(A + (long)(m0 + r * 32 + srow) * Lq + (kk) + scolS,                 \
                &AS[r * 2048 + sdst]);                                              \
    _Pragma("unroll")                                                               \
    for (int r = 0; r < 2; ++r)  /* B: 64 rows = 2 rounds */                        \
        gload16(B + (long)(n0 + r * 32 + srow) * Lq + (kk) + scolS,                 \
                &BS[r * 2048 + sdst]);                                              \
} while (0)

#define CMP(AS, BS) do {                                                            \
    _Pragma("unroll")                                                               \
    for (int ks = 0; ks < 2; ++ks) {                                                \
        int slot = ((ks * 4 + quad) ^ xr) << 3;                                     \
        bf16x8 a0 = *(const bf16x8*)&AS[(wr * 32 +      l16) * 64 + slot];          \
        bf16x8 a1 = *(const bf16x8*)&AS[(wr * 32 + 16 + l16) * 64 + slot];          \
        bf16x8 b0 = *(const bf16x8*)&BS[(wc * 32 +      l16) * 64 + slot];          \
        bf16x8 b1 = *(const bf16x8*)&BS[(wc * 32 + 16 + l16) * 64 + slot];          \
        acc[0][0] = __builtin_amdgcn_mfma_f32_16x16x32_bf16(a0, b0, acc[0][0], 0, 0, 0); \
        acc[0][1] = __builtin_amdgcn_mfma_f32_16x16x32_bf16(a0, b1, acc[0][1], 0, 0, 0); \
        acc[1][0] = __builtin_amdgcn_mfma_f32_16x16x32_bf16(a1, b0, acc[1][0], 0, 0, 0); \
        acc[1][1] = __builtin_amdgcn_mfma_f32_16x16x32_bf16(a1, b1, acc[1][1], 0, 0, 0); \
    }                                                                               \
} while (0)

#define SBAR() do { __builtin_amdgcn_s_barrier(); asm volatile("" ::: "memory"); } while (0)
#define WAITV4() do { asm volatile("s_waitcnt vmcnt(4)" ::: "memory"); __builtin_amdgcn_sched_barrier(0); } while (0)
#define WAITV0() do { asm volatile("s_waitcnt vmcnt(0)" ::: "memory"); __builtin_amdgcn_sched_barrier(0); } while (0)

    STG(As0, Bs0, 0);                         // tile 0: 4 loads in flight
    STG(As1, Bs1, 64);                        // tile 1: 8 in flight
    for (int k0 = 0; k0 < Lq; k0 += 128) {
        WAITV4();                             // oldest 4 (As0/Bs0 tile) landed
        SBAR();                               // all waves see it
        CMP(As0, Bs0);
        SBAR();                               // all waves done reading As0/Bs0
        if (k0 + 128 < Lq) STG(As0, Bs0, k0 + 128);   // 2 tiles ahead; back to 8 in flight
        if (k0 + 128 < Lq) WAITV4(); else WAITV0();   // As1/Bs1 tile landed
        SBAR();
        CMP(As1, Bs1);
        SBAR();
        if (k0 + 192 < Lq) STG(As1, Bs1, k0 + 192);
    }
#undef STG
#undef CMP
#undef SBAR
#undef WAITV4
#undef WAITV0
#pragma unroll
    for (int i = 0; i < 2; ++i) {
        int mrow = m0 + wr * 32 + i * 16 + quad * 4;
#pragma unroll
        for (int j = 0; j < 2; ++j) {
            int ncol = n0 + wc * 32 + j * 16 + l16;
#pragma unroll
            for (int r = 0; r < 4; ++r)
                C[(long)(mrow + r) * Lq + ncol] = acc[i][j][r];
        }
    }
}

// ---------------- literal conv epilogue: fp32 tap-sum, /4, store fp32 (r11-verified) ----------------
__global__ __launch_bounds__(256) void k_epi2(const float* __restrict__ P, float* __restrict__ out) {
    int idx = blockIdx.x * 256 + threadIdx.x;   // 1048576
    int ox = idx & 63, oy = (idx >> 6) & 63, c = (idx >> 12) & 127, bb = idx >> 19;
    const float* Pb = P + (long)bb * 2048 * Lq;
    float s = 0.f;
#pragma unroll
    for (int u = 0; u < 4; ++u) {
        int t = oy + u - 2;
        if (t & 1) continue;
        int iy = t >> 1;
        if ((unsigned)iy >= (unsigned)HS) continue;
#pragma unroll
        for (int v = 0; v < 4; ++v) {
            int r = ox + v - 2;
            if (r & 1) continue;
            int ix = r >> 1;
            if ((unsigned)ix >= (unsigned)HS) continue;
            s += Pb[(long)((c << 4) + (3 - u) * 4 + (3 - v)) * Lq + (iy << 5) + ix];
        }
    }
    out[idx] = 0.25f * s;
}

extern "C" void kernel_launch(void* const* d_in, const int* in_sizes, int n_in,
                              void* d_out, int out_size, void* d_ws, size_t ws_size,
                              hipStream_t stream) {
    const float* f    = (const float*)d_in[0];
    const float* bsrc = (const float*)d_in[1];
    const float* mask = (const float*)d_in[2];
    float* out = (float*)d_out;
    float* ws = (float*)d_ws;

    // workspace (floats): ~8.9M = 35.7 MB
    float* ssq   = ws;                        // 2048
    float* norms = ssq   + 2048;              // 2048
    float* mmb   = norms + 2048;              // 1024
    unsigned short* fH = (unsigned short*)(mmb + 1024);      // 262144 ushorts each
    unsigned short* fL = fH + 262144;
    unsigned short* bH = fL + 262144;
    unsigned short* bL = bH + 262144;
    float* GTa   = (float*)(bL + 262144);     // 2097152 : GT -> attnT(bf16)
    float* C1    = GTa + 2097152;             // 2097152 : S0T -> P[0:2M]
    float* C2    = C1  + 2097152;             // 2097152 : S2T -> P[2M:4M]
    unsigned short* Wm = (unsigned short*)(C2 + 2097152);    // 4194304 ushorts
    float* S0T  = C1;
    float* S2T  = C2;
    unsigned short* attnT = (unsigned short*)GTa;  // GT dead after k_s0T
    float* P    = C1;      // spans C1+C2; S0T dead after fuse12, S2T dead after softmax

    hipLaunchKernelGGL(k_prep3,     dim3(16896),      dim3(256), 0, stream, f, bsrc, fH, fL, bH, bL, ssq, Wm);
    hipLaunchKernelGGL(k_gram,      dim3(16, 16, 3),  dim3(256), 0, stream, fH, fL, bH, bL, GTa, ssq, mask, norms, mmb);
    hipLaunchKernelGGL(k_s0T,       dim3(8192),       dim3(256), 0, stream, GTa, norms, S0T);
    hipLaunchKernelGGL(k_fuse12,    dim3(8192),       dim3(256), 0, stream, S0T, S2T);
    hipLaunchKernelGGL(k_softmaxT,  dim3(512),        dim3(256), 0, stream, S2T, mmb, attnT);
    hipLaunchKernelGGL(k_gemm_mfma, dim3(32, 16, 2),  dim3(256), 0, stream, Wm, attnT, P);
    hipLaunchKernelGGL(k_epi2,      dim3(4096),       dim3(256), 0, stream, P, out);
}